// Round 1
// baseline (1186.127 us; speedup 1.0000x reference)
//
#include <hip/hip_runtime.h>
#include <cstdint>
#include <cstddef>

#define BSZ 4
#define SEQL 2048
#define DDIM 512
#define AHID 128
#define NROWS (BSZ*SEQL)        // 8192
#define MTE 8256                // 8192 rows + t0 row + pad to 64
#define NANG (NROWS*6)          // 49152

__device__ __forceinline__ float gelu_f(float x){
  return 0.5f * x * (1.0f + erff(x * 0.7071067811865475f));
}

// ---- segment scan: seg id (cumsum cls), valid flag, per batch (one wave) ----
__global__ void scan_kernel(const int* __restrict__ aa, int* __restrict__ seg,
                            int* __restrict__ valid){
  int b = blockIdx.x;
  int lane = threadIdx.x;            // 64 lanes
  const int CH = SEQL/64;            // 32
  int base = b*SEQL + lane*CH;
  int av[CH];
  int lc=0, le=0;
  #pragma unroll
  for (int i=0;i<CH;i++){ int a=aa[base+i]; av[i]=a; lc += (a==0); le += (a==2); }
  int pc=lc, pe=le;
  #pragma unroll
  for (int off=1; off<64; off<<=1){
    int tc = __shfl_up(pc, off);
    int te = __shfl_up(pe, off);
    if (lane >= off){ pc += tc; pe += te; }
  }
  int c = pc - lc, eo = pe - le;     // exclusive prefixes
  #pragma unroll
  for (int i=0;i<CH;i++){
    int a = av[i];
    c += (a==0); eo += (a==2);
    seg[base+i] = c;
    valid[base+i] = (c>eo) && (a!=0) && (a!=2);
  }
}

// ---- per-row mean pairwise distance within segment (one wave per row) ----
__global__ void dist_kernel(const float* __restrict__ pos, const int* __restrict__ seg,
                            const int* __restrict__ valid, float* __restrict__ dist){
  int gw = (int)((blockIdx.x * blockDim.x + threadIdx.x) >> 6);
  int lane = threadIdx.x & 63;
  if (gw >= NROWS) return;
  float out = 0.f;
  if (valid[gw]){
    int b = gw / SEQL;
    int sg = seg[gw];
    float px = pos[(size_t)gw*9+3], py = pos[(size_t)gw*9+4], pz = pos[(size_t)gw*9+5];
    float s = 0.f; int cnt = 0;
    int rowbase = b*SEQL;
    for (int j = lane; j < SEQL; j += 64){
      int idx = rowbase + j;
      if (valid[idx] && seg[idx]==sg){
        float dx = px - pos[(size_t)idx*9+3];
        float dy = py - pos[(size_t)idx*9+4];
        float dz = pz - pos[(size_t)idx*9+5];
        float sq = dx*dx+dy*dy+dz*dz;
        s += (sq>0.f) ? sqrtf(sq) : 0.f;
        cnt += 1;
      }
    }
    #pragma unroll
    for (int off=32; off>0; off>>=1){
      s   += __shfl_down(s, off);
      cnt += __shfl_down(cnt, off);
    }
    out = s / (float)(cnt > 0 ? cnt : 1);
  }
  if (lane==0) dist[gw] = out;
}

// ---- sinusoidal embedding rows: 8192 real rows + t=0 rows (8192..8255) ----
__global__ void sinemb_kernel(const float* __restrict__ time_pos, float* __restrict__ e){
  size_t idx = (size_t)blockIdx.x*256 + threadIdx.x;
  if (idx >= (size_t)MTE*DDIM) return;
  int row = (int)(idx >> 9);
  int d = (int)(idx & 511);
  float t = (row < NROWS) ? time_pos[row] : 0.f;
  int k = d & 255;
  float f = expf((-9.210340371976184f * (float)k) * (1.0f/256.0f));
  float a = t * f;
  e[idx] = (d < 256) ? sinf(a) : cosf(a);
}

// ---- generic fp32 GEMM: C[M,N] = act(A[M,K] @ B[K,N] + bias) ----
// 64x64 tile, 256 threads, 4x4 microtile. M%64==0, N%64==0, K%16==0 required.
template<bool GELU, bool HASBIAS>
__launch_bounds__(256)
__global__ void gemm_f32(const float* __restrict__ A, const float* __restrict__ B,
                         const float* __restrict__ bias, float* __restrict__ C,
                         int M, int N, int K, int ldc){
  __shared__ float As[16][65];
  __shared__ float Bs[16][65];
  int bm = blockIdx.y * 64;
  int bn = blockIdx.x * 64;
  int tid = threadIdx.x;
  int tx = tid & 15, ty = tid >> 4;
  float acc[4][4] = {{0.f,0.f,0.f,0.f},{0.f,0.f,0.f,0.f},{0.f,0.f,0.f,0.f},{0.f,0.f,0.f,0.f}};
  int ar = tid >> 2;            // 0..63 (A row in tile)
  int ac = (tid & 3) * 4;       // 0,4,8,12 (A col group)
  int br = tid >> 4;            // 0..15  (B row in tile)
  int bc = (tid & 15) * 4;      // 0..60  (B col group)
  const float* Abase = A + (size_t)(bm+ar)*K + ac;
  const float* Bbase = B + (size_t)br*N + bn + bc;
  for (int k0 = 0; k0 < K; k0 += 16){
    float4 av = *(const float4*)(Abase + k0);
    float4 bv = *(const float4*)(Bbase + (size_t)k0*N);
    As[ac+0][ar]=av.x; As[ac+1][ar]=av.y; As[ac+2][ar]=av.z; As[ac+3][ar]=av.w;
    Bs[br][bc+0]=bv.x; Bs[br][bc+1]=bv.y; Bs[br][bc+2]=bv.z; Bs[br][bc+3]=bv.w;
    __syncthreads();
    #pragma unroll
    for (int k=0;k<16;k++){
      float a0=As[k][ty*4+0],a1=As[k][ty*4+1],a2=As[k][ty*4+2],a3=As[k][ty*4+3];
      float b0=Bs[k][tx*4+0],b1=Bs[k][tx*4+1],b2=Bs[k][tx*4+2],b3=Bs[k][tx*4+3];
      acc[0][0]+=a0*b0; acc[0][1]+=a0*b1; acc[0][2]+=a0*b2; acc[0][3]+=a0*b3;
      acc[1][0]+=a1*b0; acc[1][1]+=a1*b1; acc[1][2]+=a1*b2; acc[1][3]+=a1*b3;
      acc[2][0]+=a2*b0; acc[2][1]+=a2*b1; acc[2][2]+=a2*b2; acc[2][3]+=a2*b3;
      acc[3][0]+=a3*b0; acc[3][1]+=a3*b1; acc[3][2]+=a3*b2; acc[3][3]+=a3*b3;
    }
    __syncthreads();
  }
  #pragma unroll
  for (int i=0;i<4;i++){
    int r = bm + ty*4 + i;
    if (r >= M) continue;
    #pragma unroll
    for (int j=0;j<4;j++){
      int cc = bn + tx*4 + j;
      float v = acc[i][j];
      if (HASBIAS) v += bias[cc];
      if (GELU) v = gelu_f(v);
      C[(size_t)r*ldc + cc] = v;
    }
  }
}

// ---- angle hidden: H[49152,128] = gelu((amask? angle:0) * ang_w1[k]) ----
__global__ void anghid_kernel(const float* __restrict__ angle, const int* __restrict__ angm,
                              const int* __restrict__ bondm, const float* __restrict__ w1,
                              float* __restrict__ H){
  size_t idx = (size_t)blockIdx.x*256 + threadIdx.x;
  if (idx >= (size_t)NANG*AHID) return;
  int row = (int)(idx >> 7);
  int k = (int)(idx & 127);
  int b = row / (SEQL*6);
  int r = row - b*(SEQL*6);
  int l = r / 6, j = r - l*6;
  int bl = b*SEQL + l;
  int m = (j<3) ? angm[bl*3+j] : bondm[bl*3+(j-3)];
  float x = m ? angle[bl*6+j] : 0.f;
  H[idx] = gelu_f(x * w1[k]);
}

// ---- assemble AF: base (or unkang) + time-embedding (E row or t0) ----
__global__ void assemble_kernel(float* __restrict__ AF, const int* __restrict__ angm,
                                const int* __restrict__ bondm, const int* __restrict__ mask_angle,
                                const int* __restrict__ aa, const float* __restrict__ E,
                                const float* __restrict__ t0, const float* __restrict__ unkang){
  size_t idx = (size_t)blockIdx.x*256 + threadIdx.x;
  if (idx >= (size_t)NANG*DDIM) return;
  int row = (int)(idx >> 9);
  int d = (int)(idx & 511);
  int b = row / (SEQL*6);
  int r = row - b*(SEQL*6);          // r = 6*l + j in [0, 6L)
  int l = r / 6, j = r - l*6;
  int bl = b*SEQL + l;
  int am = (j<3) ? angm[bl*3+j] : bondm[bl*3+(j-3)];
  int l2 = r & (SEQL-1);             // tile(.,(1,6,1)) quirk: mask index = (6l+j) mod L
  int bl2 = b*SEQL + l2;
  int a2 = aa[bl2];
  bool tm = mask_angle[bl2] && (a2!=0) && (a2!=2);
  float base = am ? AF[idx] : unkang[d];
  float te = (tm && am) ? E[(size_t)bl*DDIM + d] : t0[d];
  AF[idx] = base + te;
}

// ---- pos feature: (pos_mask? gelu(dist*w1)*w2 : unkpos) + temb_pos ----
__global__ void posfeat_kernel(const float* __restrict__ dist, const int* __restrict__ aa,
                               const int* __restrict__ mask_angle, const float* __restrict__ pw1,
                               const float* __restrict__ pw2, const float* __restrict__ unkpos,
                               const float* __restrict__ E, const float* __restrict__ t0,
                               float* __restrict__ PF){
  size_t idx = (size_t)blockIdx.x*256 + threadIdx.x;
  if (idx >= (size_t)NROWS*DDIM) return;
  int row = (int)(idx >> 9);
  int d = (int)(idx & 511);
  int a = aa[row];
  bool ce = (a==0) || (a==2);
  float base = ce ? unkpos[d] : gelu_f(dist[row]*pw1[0]) * pw2[d];
  bool tm = mask_angle[row] && !ce;
  float te = tm ? E[(size_t)row*DDIM + d] : t0[d];
  PF[idx] = base + te;
}

// ---- final overrides: cls row, eos row, padding zero ----
__global__ void finalize_kernel(float* __restrict__ out, const int* __restrict__ aa,
                                const int* __restrict__ pad, const float* __restrict__ cls_w,
                                const float* __restrict__ eos_w){
  size_t idx = (size_t)blockIdx.x*256 + threadIdx.x;
  if (idx >= (size_t)NROWS*1024) return;
  int row = (int)(idx >> 10);
  int d = (int)(idx & 1023);
  int a = aa[row];
  float v = out[idx];
  if (a==0) v = cls_w[d];
  if (a==2) v = eos_w[d];
  if (pad[row]) v = 0.f;
  out[idx] = v;
}

extern "C" void kernel_launch(void* const* d_in, const int* in_sizes, int n_in,
                              void* d_out, int out_size, void* d_ws, size_t ws_size,
                              hipStream_t stream){
  const float* pos        = (const float*)d_in[0];
  const float* angle      = (const float*)d_in[1];
  const int*   padm       = (const int*)d_in[2];
  // d_in[3]=mask_aa, d_in[4]=mask_pos: unused by reference
  const int*   mask_angle = (const int*)d_in[5];
  const int*   angle_mask = (const int*)d_in[6];
  const int*   bond_mask  = (const int*)d_in[7];
  const float* time_pos   = (const float*)d_in[8];
  // d_in[9]=time_angle: unused (overwritten in reference)
  const int*   aa         = (const int*)d_in[10];
  const float* ang_w1     = (const float*)d_in[11];
  const float* ang_w2     = (const float*)d_in[12];
  const float* pos_w1     = (const float*)d_in[13];
  const float* pos_w2     = (const float*)d_in[14];
  const float* te_w1      = (const float*)d_in[15];
  const float* te_b1      = (const float*)d_in[16];
  const float* te_w2      = (const float*)d_in[17];
  const float* te_b2      = (const float*)d_in[18];
  const float* angproj_w  = (const float*)d_in[19];
  const float* angproj_b  = (const float*)d_in[20];
  const float* posproj_w  = (const float*)d_in[21];
  const float* posproj_b  = (const float*)d_in[22];
  const float* cls_w      = (const float*)d_in[23];
  const float* eos_w      = (const float*)d_in[24];
  const float* unkang     = (const float*)d_in[25];
  const float* unkpos     = (const float*)d_in[26];

  char* ws = (char*)d_ws;
  size_t off = 0;
  auto alloc = [&](size_t bytes)->char*{
    char* p = ws + off;
    off += (bytes + 255) & ~(size_t)255;
    return p;
  };
  int*   seg   = (int*)  alloc((size_t)NROWS*4);
  int*   valid = (int*)  alloc((size_t)NROWS*4);
  float* dist  = (float*)alloc((size_t)NROWS*4);
  float* e     = (float*)alloc((size_t)MTE*DDIM*4);
  float* H1    = (float*)alloc((size_t)MTE*DDIM*4);
  float* E     = (float*)alloc((size_t)MTE*DDIM*4);
  float* Hang  = (float*)alloc((size_t)NANG*AHID*4);
  float* AF    = (float*)alloc((size_t)NANG*DDIM*4);
  float* PF    = (float*)alloc((size_t)NROWS*DDIM*4);
  const float* t0 = E + (size_t)NROWS*DDIM;   // row 8192 of E = TE(0)

  float* out = (float*)d_out;
  dim3 blk(256);

  // 1. segment scan + distances
  scan_kernel<<<dim3(BSZ), dim3(64), 0, stream>>>(aa, seg, valid);
  dist_kernel<<<dim3(NROWS/4), blk, 0, stream>>>(pos, seg, valid, dist);

  // 2. time embedding: sinusoid rows, then 2-layer MLP (8256 rows incl. t0)
  sinemb_kernel<<<dim3((MTE*DDIM)/256), blk, 0, stream>>>(time_pos, e);
  gemm_f32<true,true><<<dim3(DDIM/64, MTE/64), blk, 0, stream>>>(e, te_w1, te_b1, H1, MTE, DDIM, DDIM, DDIM);
  gemm_f32<false,true><<<dim3(DDIM/64, MTE/64), blk, 0, stream>>>(H1, te_w2, te_b2, E, MTE, DDIM, DDIM, DDIM);

  // 3. angle feature base: hidden + GEMM
  anghid_kernel<<<dim3((NANG*AHID)/256), blk, 0, stream>>>(angle, angle_mask, bond_mask, ang_w1, Hang);
  gemm_f32<false,false><<<dim3(DDIM/64, NANG/64), blk, 0, stream>>>(Hang, ang_w2, nullptr, AF, NANG, DDIM, AHID, DDIM);

  // 4. assemble AF = (masked base|unkang) + (E row | t0) with tile quirk
  assemble_kernel<<<dim3((NANG*DDIM)/256), blk, 0, stream>>>(AF, angle_mask, bond_mask, mask_angle, aa, E, t0, unkang);

  // 5. angle projection: [8192,3072] @ [3072,512] -> out[:, :512]
  gemm_f32<false,true><<<dim3(DDIM/64, NROWS/64), blk, 0, stream>>>(AF, angproj_w, angproj_b, out, NROWS, DDIM, 6*DDIM, 1024);

  // 6. pos feature + projection -> out[:, 512:]
  posfeat_kernel<<<dim3((NROWS*DDIM)/256), blk, 0, stream>>>(dist, aa, mask_angle, pos_w1, pos_w2, unkpos, E, t0, PF);
  gemm_f32<false,true><<<dim3(DDIM/64, NROWS/64), blk, 0, stream>>>(PF, posproj_w, posproj_b, out + DDIM, NROWS, DDIM, DDIM, 1024);

  // 7. cls/eos/padding overrides
  finalize_kernel<<<dim3((NROWS*1024)/256), blk, 0, stream>>>(out, aa, padm, cls_w, eos_w);
}

// Round 2
// 414.669 us; speedup vs baseline: 2.8604x; 2.8604x over previous
//
#include <hip/hip_runtime.h>
#include <hip/hip_bf16.h>
#include <cstdint>
#include <cstddef>

#define BSZ 4
#define SEQL 2048
#define DDIM 512
#define AHID 128
#define NROWS (BSZ*SEQL)        // 8192
#define MTE 8320                // 8192 rows + t0 rows, padded to 128
#define T0ROW 8192
#define NANG (NROWS*6)          // 49152

typedef __attribute__((ext_vector_type(8))) short short8;
typedef __attribute__((ext_vector_type(4))) float f32x4;
typedef __hip_bfloat16 bf16;

__device__ __forceinline__ float gelu_f(float x){
  return 0.5f * x * (1.0f + erff(x * 0.7071067811865475f));
}

__device__ __forceinline__ void gload16(const void* g, void* l){
  __builtin_amdgcn_global_load_lds(
      (const __attribute__((address_space(1))) unsigned int*)g,
      (__attribute__((address_space(3))) unsigned int*)l,
      16, 0, 0);
}

// ---- segment scan: seg id (cumsum cls), valid flag, per batch (one wave) ----
__global__ void scan_kernel(const int* __restrict__ aa, int* __restrict__ seg,
                            int* __restrict__ valid){
  int b = blockIdx.x;
  int lane = threadIdx.x;            // 64 lanes
  const int CH = SEQL/64;            // 32
  int base = b*SEQL + lane*CH;
  int av[CH];
  int lc=0, le=0;
  #pragma unroll
  for (int i=0;i<CH;i++){ int a=aa[base+i]; av[i]=a; lc += (a==0); le += (a==2); }
  int pc=lc, pe=le;
  #pragma unroll
  for (int off=1; off<64; off<<=1){
    int tc = __shfl_up(pc, off);
    int te = __shfl_up(pe, off);
    if (lane >= off){ pc += tc; pe += te; }
  }
  int c = pc - lc, eo = pe - le;     // exclusive prefixes
  #pragma unroll
  for (int i=0;i<CH;i++){
    int a = av[i];
    c += (a==0); eo += (a==2);
    seg[base+i] = c;
    valid[base+i] = (c>eo) && (a!=0) && (a!=2);
  }
}

// ---- per-row mean pairwise distance within segment (one wave per row) ----
__global__ void dist_kernel(const float* __restrict__ pos, const int* __restrict__ seg,
                            const int* __restrict__ valid, float* __restrict__ dist){
  int gw = (int)((blockIdx.x * blockDim.x + threadIdx.x) >> 6);
  int lane = threadIdx.x & 63;
  if (gw >= NROWS) return;
  float out = 0.f;
  if (valid[gw]){
    int b = gw / SEQL;
    int sg = seg[gw];
    float px = pos[(size_t)gw*9+3], py = pos[(size_t)gw*9+4], pz = pos[(size_t)gw*9+5];
    float s = 0.f; int cnt = 0;
    int rowbase = b*SEQL;
    for (int j = lane; j < SEQL; j += 64){
      int idx = rowbase + j;
      if (valid[idx] && seg[idx]==sg){
        float dx = px - pos[(size_t)idx*9+3];
        float dy = py - pos[(size_t)idx*9+4];
        float dz = pz - pos[(size_t)idx*9+5];
        float sq = dx*dx+dy*dy+dz*dz;
        s += (sq>0.f) ? sqrtf(sq) : 0.f;
        cnt += 1;
      }
    }
    #pragma unroll
    for (int off=32; off>0; off>>=1){
      s   += __shfl_down(s, off);
      cnt += __shfl_down(cnt, off);
    }
    out = s / (float)(cnt > 0 ? cnt : 1);
  }
  if (lane==0) dist[gw] = out;
}

// ---- sinusoidal rows (bf16): 8192 real + t=0 rows (8192..8319) ----
__global__ void sinemb_kernel(const float* __restrict__ time_pos, bf16* __restrict__ e){
  size_t idx = (size_t)blockIdx.x*256 + threadIdx.x;
  if (idx >= (size_t)MTE*DDIM) return;
  int row = (int)(idx >> 9);
  int d = (int)(idx & 511);
  float t = (row < NROWS) ? time_pos[row] : 0.f;
  int k = d & 255;
  float f = expf(-9.210340371976184f * (float)k * (1.0f/256.0f));
  float a = t * f;
  e[idx] = __float2bfloat16((d < 256) ? sinf(a) : cosf(a));
}

// ---- transpose + convert: W[K,N] fp32 -> Wt[N,K] bf16 ----
__global__ void transpose_bf16_kernel(const float* __restrict__ W, bf16* __restrict__ Wt,
                                      int K, int N){
  __shared__ float t[32][33];
  int k0 = blockIdx.y*32, n0 = blockIdx.x*32;
  int tx = threadIdx.x & 31, ty = threadIdx.x >> 5;   // 32 x 8
  #pragma unroll
  for (int i=0;i<32;i+=8)
    t[ty+i][tx] = W[(size_t)(k0+ty+i)*N + n0+tx];
  __syncthreads();
  #pragma unroll
  for (int i=0;i<32;i+=8)
    Wt[(size_t)(n0+ty+i)*K + k0+tx] = __float2bfloat16(t[tx][ty+i]);
}

// ---- per-ang-row masks: amask (angle valid), teidx (E row for time emb) ----
__global__ void prep_ang_kernel(const int* __restrict__ angm, const int* __restrict__ bondm,
                                const int* __restrict__ mask_angle, const int* __restrict__ aa,
                                unsigned char* __restrict__ amask8, int* __restrict__ teidx){
  int r = blockIdx.x*256 + threadIdx.x;
  if (r >= NANG) return;
  int b = r / (SEQL*6);
  int rr = r - b*(SEQL*6);
  int l = rr / 6, j = rr - l*6;
  int bl = b*SEQL + l;
  int am = (j<3) ? angm[bl*3+j] : bondm[bl*3+(j-3)];
  int l2 = rr & (SEQL-1);            // tile(.,(1,6,1)) quirk
  int bl2 = b*SEQL + l2;
  int a2 = aa[bl2];
  int tm = mask_angle[bl2] && (a2!=0) && (a2!=2);
  amask8[r] = (unsigned char)(am != 0);
  teidx[r] = (tm && am) ? bl : T0ROW;
}

// ---- angle hidden (bf16): H[49152,128] = gelu((amask? angle:0) * w1[k]) ----
__global__ void anghid_kernel(const float* __restrict__ angle, const int* __restrict__ angm,
                              const int* __restrict__ bondm, const float* __restrict__ w1,
                              bf16* __restrict__ H){
  size_t idx = (size_t)blockIdx.x*256 + threadIdx.x;
  if (idx >= (size_t)NANG*AHID) return;
  int row = (int)(idx >> 7);
  int k = (int)(idx & 127);
  int b = row / (SEQL*6);
  int rr = row - b*(SEQL*6);
  int l = rr / 6, j = rr - l*6;
  int bl = b*SEQL + l;
  int m = (j<3) ? angm[bl*3+j] : bondm[bl*3+(j-3)];
  float x = m ? angle[bl*6+j] : 0.f;
  H[idx] = __float2bfloat16(gelu_f(x * w1[k]));
}

// ---- pos feature (bf16): (pos_mask? gelu(dist*w1)*w2 : unkpos) + temb ----
__global__ void posfeat_kernel(const float* __restrict__ dist, const int* __restrict__ aa,
                               const int* __restrict__ mask_angle, const float* __restrict__ pw1,
                               const float* __restrict__ pw2, const float* __restrict__ unkpos,
                               const bf16* __restrict__ E, bf16* __restrict__ PF){
  size_t idx = (size_t)blockIdx.x*256 + threadIdx.x;
  if (idx >= (size_t)NROWS*DDIM) return;
  int row = (int)(idx >> 9);
  int d = (int)(idx & 511);
  int a = aa[row];
  bool ce = (a==0) || (a==2);
  float base = ce ? unkpos[d] : gelu_f(dist[row]*pw1[0]) * pw2[d];
  bool tm = mask_angle[row] && !ce;
  float te = __bfloat162float(E[(size_t)(tm ? row : T0ROW)*DDIM + d]);
  PF[idx] = __float2bfloat16(base + te);
}

// ================= bf16 MFMA GEMM: C = A[M,K] @ Bt[N,K]^T =================
// 128x128 tile, 256 threads (4 waves 2x2), 16x16x32 MFMA, BK=32.
// LDS staged via global_load_lds(16B); chunk-XOR swizzle for conflict-free
// ds_read_b128 fragment reads (phys_chunk = logical ^ ((row>>1)&3)).
// EPI: 0 = gelu(v+bias)->bf16, 1 = v+bias->bf16,
//      2 = assemble: (am? v: unk[c]) + E[teidx[r]][c] -> bf16,
//      3 = final: v+bias, cls/eos/pad overrides -> fp32
struct EpiArgs {
  const float* bias;
  const bf16*  E;
  const int*   teidx;
  const unsigned char* amask;
  const float* unk;
  const int*   aa;
  const int*   pad;
  const float* cls;
  const float* eos;
  float*       outF;
  bf16*        outB;
  int          ldc;
};

template<int EPI>
__launch_bounds__(256)
__global__ void gemm_bf16(const bf16* __restrict__ A, const bf16* __restrict__ Bt,
                          int M, int N, int K, EpiArgs ea){
  __shared__ char Al[128*32*2];
  __shared__ char Bl[128*32*2];
  const int tid = threadIdx.x;
  const int wave = tid >> 6, lane = tid & 63;
  const int bm = blockIdx.y * 128, bn = blockIdx.x * 128;

  // staging: each wave loads 2 chunks (16 rows x 32 cols) of A and of B
  const int r0 = (wave*2+0)*16 + (lane>>2);
  const int r1 = (wave*2+1)*16 + (lane>>2);
  const int ch = lane & 3;
  const int cg0 = ch ^ ((r0>>1)&3);
  const int cg1 = ch ^ ((r1>>1)&3);
  const char* gA0 = (const char*)(A  + (size_t)(bm+r0)*K + cg0*8);
  const char* gA1 = (const char*)(A  + (size_t)(bm+r1)*K + cg1*8);
  const char* gB0 = (const char*)(Bt + (size_t)(bn+r0)*K + cg0*8);
  const char* gB1 = (const char*)(Bt + (size_t)(bn+r1)*K + cg1*8);
  char* lA0 = Al + (wave*2+0)*1024;
  char* lA1 = Al + (wave*2+1)*1024;
  char* lB0 = Bl + (wave*2+0)*1024;
  char* lB1 = Bl + (wave*2+1)*1024;

  const int wm = (wave>>1)*64, wn = (wave&1)*64;
  const int lm = lane & 15;          // m (resp. n) within 16-tile
  const int kq = lane >> 4;          // k-quad 0..3
  const int sw = kq ^ ((lm>>1)&3);   // swizzled physical chunk
  const int aoff = (wm+lm)*64 + sw*16;
  const int boff = (wn+lm)*64 + sw*16;

  f32x4 acc[4][4];
  #pragma unroll
  for (int i=0;i<4;i++)
    #pragma unroll
    for (int j=0;j<4;j++) acc[i][j] = (f32x4){0.f,0.f,0.f,0.f};

  for (int k0 = 0; k0 < K; k0 += 32){
    gload16(gA0 + (size_t)k0*2, lA0);
    gload16(gA1 + (size_t)k0*2, lA1);
    gload16(gB0 + (size_t)k0*2, lB0);
    gload16(gB1 + (size_t)k0*2, lB1);
    __syncthreads();
    short8 af[4], bfr[4];
    #pragma unroll
    for (int t=0;t<4;t++){
      af[t]  = *(const short8*)(Al + aoff + t*1024);
      bfr[t] = *(const short8*)(Bl + boff + t*1024);
    }
    #pragma unroll
    for (int mt=0;mt<4;mt++)
      #pragma unroll
      for (int nt=0;nt<4;nt++)
        acc[mt][nt] = __builtin_amdgcn_mfma_f32_16x16x32_bf16(af[mt], bfr[nt], acc[mt][nt], 0, 0, 0);
    __syncthreads();
  }

  // epilogue: C/D layout col=lane&15, row=(lane>>4)*4+reg  [m89-verified]
  #pragma unroll
  for (int mt=0;mt<4;mt++){
    #pragma unroll
    for (int r=0;r<4;r++){
      int row = bm + wm + mt*16 + kq*4 + r;
      #pragma unroll
      for (int nt=0;nt<4;nt++){
        int col = bn + wn + nt*16 + lm;
        float v = acc[mt][nt][r];
        if (EPI==0){
          ea.outB[(size_t)row*ea.ldc + col] = __float2bfloat16(gelu_f(v + ea.bias[col]));
        } else if (EPI==1){
          ea.outB[(size_t)row*ea.ldc + col] = __float2bfloat16(v + ea.bias[col]);
        } else if (EPI==2){
          float v2 = ea.amask[row] ? v : ea.unk[col];
          v2 += __bfloat162float(ea.E[(size_t)ea.teidx[row]*DDIM + col]);
          ea.outB[(size_t)row*ea.ldc + col] = __float2bfloat16(v2);
        } else {
          float v2 = v + ea.bias[col];
          int a = ea.aa[row];
          if (a==0) v2 = ea.cls[col];
          else if (a==2) v2 = ea.eos[col];
          if (ea.pad[row]) v2 = 0.f;
          ea.outF[(size_t)row*ea.ldc + col] = v2;
        }
      }
    }
  }
}

extern "C" void kernel_launch(void* const* d_in, const int* in_sizes, int n_in,
                              void* d_out, int out_size, void* d_ws, size_t ws_size,
                              hipStream_t stream){
  const float* pos        = (const float*)d_in[0];
  const float* angle      = (const float*)d_in[1];
  const int*   padm       = (const int*)d_in[2];
  const int*   mask_angle = (const int*)d_in[5];
  const int*   angle_mask = (const int*)d_in[6];
  const int*   bond_mask  = (const int*)d_in[7];
  const float* time_pos   = (const float*)d_in[8];
  const int*   aa         = (const int*)d_in[10];
  const float* ang_w1     = (const float*)d_in[11];
  const float* ang_w2     = (const float*)d_in[12];
  const float* pos_w1     = (const float*)d_in[13];
  const float* pos_w2     = (const float*)d_in[14];
  const float* te_w1      = (const float*)d_in[15];
  const float* te_b1      = (const float*)d_in[16];
  const float* te_w2      = (const float*)d_in[17];
  const float* te_b2      = (const float*)d_in[18];
  const float* angproj_w  = (const float*)d_in[19];
  const float* angproj_b  = (const float*)d_in[20];
  const float* posproj_w  = (const float*)d_in[21];
  const float* posproj_b  = (const float*)d_in[22];
  const float* cls_w      = (const float*)d_in[23];
  const float* eos_w      = (const float*)d_in[24];
  const float* unkang     = (const float*)d_in[25];
  const float* unkpos     = (const float*)d_in[26];

  char* ws = (char*)d_ws;
  size_t off = 0;
  auto alloc = [&](size_t bytes)->char*{
    char* p = ws + off;
    off += (bytes + 255) & ~(size_t)255;
    return p;
  };
  int*   seg    = (int*)  alloc((size_t)NROWS*4);
  int*   valid  = (int*)  alloc((size_t)NROWS*4);
  float* dist   = (float*)alloc((size_t)NROWS*4);
  unsigned char* amask8 = (unsigned char*)alloc(NANG);
  int*   teidx  = (int*)  alloc((size_t)NANG*4);
  bf16*  e      = (bf16*) alloc((size_t)MTE*DDIM*2);
  bf16*  H1     = (bf16*) alloc((size_t)MTE*DDIM*2);
  bf16*  E      = (bf16*) alloc((size_t)MTE*DDIM*2);
  bf16*  Hang   = (bf16*) alloc((size_t)NANG*AHID*2);
  bf16*  AF     = (bf16*) alloc((size_t)NANG*DDIM*2);
  bf16*  PF     = (bf16*) alloc((size_t)NROWS*DDIM*2);
  bf16*  tw1t   = (bf16*) alloc((size_t)DDIM*DDIM*2);
  bf16*  tw2t   = (bf16*) alloc((size_t)DDIM*DDIM*2);
  bf16*  aw2t   = (bf16*) alloc((size_t)DDIM*AHID*2);
  bf16*  apjt   = (bf16*) alloc((size_t)DDIM*6*DDIM*2);
  bf16*  ppjt   = (bf16*) alloc((size_t)DDIM*DDIM*2);

  float* out = (float*)d_out;
  dim3 blk(256);

  // weight transpose+convert (B^T bf16 layouts)
  transpose_bf16_kernel<<<dim3(16,16), blk, 0, stream>>>(te_w1, tw1t, DDIM, DDIM);
  transpose_bf16_kernel<<<dim3(16,16), blk, 0, stream>>>(te_w2, tw2t, DDIM, DDIM);
  transpose_bf16_kernel<<<dim3(16, 4), blk, 0, stream>>>(ang_w2, aw2t, AHID, DDIM);
  transpose_bf16_kernel<<<dim3(16,96), blk, 0, stream>>>(angproj_w, apjt, 6*DDIM, DDIM);
  transpose_bf16_kernel<<<dim3(16,16), blk, 0, stream>>>(posproj_w, ppjt, DDIM, DDIM);

  // segment scan + distances + masks
  scan_kernel<<<dim3(BSZ), dim3(64), 0, stream>>>(aa, seg, valid);
  dist_kernel<<<dim3(NROWS/4), blk, 0, stream>>>(pos, seg, valid, dist);
  prep_ang_kernel<<<dim3(NANG/256), blk, 0, stream>>>(angle_mask, bond_mask, mask_angle, aa, amask8, teidx);

  // time embedding: sinusoid rows then 2-layer MLP (8320 rows incl. t0)
  sinemb_kernel<<<dim3((MTE*DDIM)/256), blk, 0, stream>>>(time_pos, e);
  EpiArgs ea{};
  ea.bias = te_b1; ea.outB = H1; ea.ldc = DDIM;
  gemm_bf16<0><<<dim3(4, MTE/128), blk, 0, stream>>>(e, tw1t, MTE, DDIM, DDIM, ea);
  ea.bias = te_b2; ea.outB = E;
  gemm_bf16<1><<<dim3(4, MTE/128), blk, 0, stream>>>(H1, tw2t, MTE, DDIM, DDIM, ea);

  // angle base GEMM with fused assemble epilogue -> AF bf16 [49152,512]
  anghid_kernel<<<dim3((NANG*AHID)/256), blk, 0, stream>>>(angle, angle_mask, bond_mask, ang_w1, Hang);
  EpiArgs ea2{};
  ea2.E = E; ea2.teidx = teidx; ea2.amask = amask8; ea2.unk = unkang;
  ea2.outB = AF; ea2.ldc = DDIM;
  gemm_bf16<2><<<dim3(4, NANG/128), blk, 0, stream>>>(Hang, aw2t, NANG, DDIM, AHID, ea2);

  // angle projection [8192,3072]@[3072,512] with fused finalize -> out[:, :512]
  EpiArgs ea3{};
  ea3.bias = angproj_b; ea3.aa = aa; ea3.pad = padm; ea3.cls = cls_w; ea3.eos = eos_w;
  ea3.outF = out; ea3.ldc = 1024;
  gemm_bf16<3><<<dim3(4, NROWS/128), blk, 0, stream>>>(AF, apjt, NROWS, DDIM, 6*DDIM, ea3);

  // pos feature + projection with fused finalize -> out[:, 512:]
  posfeat_kernel<<<dim3((NROWS*DDIM)/256), blk, 0, stream>>>(dist, aa, mask_angle, pos_w1, pos_w2, unkpos, E, PF);
  EpiArgs ea4{};
  ea4.bias = posproj_b; ea4.aa = aa; ea4.pad = padm; ea4.cls = cls_w + DDIM; ea4.eos = eos_w + DDIM;
  ea4.outF = out + DDIM; ea4.ldc = 1024;
  gemm_bf16<3><<<dim3(4, NROWS/128), blk, 0, stream>>>(PF, ppjt, NROWS, DDIM, DDIM, ea4);
}

// Round 3
// 323.851 us; speedup vs baseline: 3.6626x; 1.2804x over previous
//
#include <hip/hip_runtime.h>
#include <hip/hip_bf16.h>
#include <cstdint>
#include <cstddef>

#define BSZ 4
#define SEQL 2048
#define DDIM 512
#define AHID 128
#define NROWS (BSZ*SEQL)        // 8192
#define MTE 8320                // 8192 rows + t0 rows, padded to 128
#define T0ROW 8192
#define NANG (NROWS*6)          // 49152

typedef __attribute__((ext_vector_type(8))) short short8;
typedef __attribute__((ext_vector_type(4))) float f32x4;
typedef __hip_bfloat16 bf16;

__device__ __forceinline__ float gelu_f(float x){
  return 0.5f * x * (1.0f + erff(x * 0.7071067811865475f));
}

__device__ __forceinline__ void gload16(const void* g, void* l){
  __builtin_amdgcn_global_load_lds(
      (const __attribute__((address_space(1))) unsigned int*)g,
      (__attribute__((address_space(3))) unsigned int*)l,
      16, 0, 0);
}

// ====================== prologue mega-kernel ======================
// blockIdx ranges: [0,NB_ANGH) anghid | [+NB_SIN) sinemb | [+NB_TR) transposes
//                  | [+NB_PREP) prep_ang | [+1) scan
#define NB_ANGH 24576   // NANG*AHID/256
#define NB_SIN  16640   // MTE*DDIM/256
#define NB_TR   2368    // 256+256+64+1536+256
#define NB_PREP 192     // NANG/256
#define NB_TOTAL (NB_ANGH+NB_SIN+NB_TR+NB_PREP+1)

__device__ void do_transpose(const float* __restrict__ W, bf16* __restrict__ Wt,
                             int K, int q, float (*tsh)[33]){
  // all weights have N=512 -> 16 n-tiles of 32; k-tiles = K/32
  int k0 = (q >> 4)*32, n0 = (q & 15)*32;
  int tx = threadIdx.x & 31, ty = threadIdx.x >> 5;   // 32 x 8
  #pragma unroll
  for (int i=0;i<32;i+=8)
    tsh[ty+i][tx] = W[(size_t)(k0+ty+i)*512 + n0+tx];
  __syncthreads();
  #pragma unroll
  for (int i=0;i<32;i+=8)
    Wt[(size_t)(n0+ty+i)*K + k0+tx] = __float2bfloat16(tsh[tx][ty+i]);
}

__global__ void prologue_kernel(const float* __restrict__ angle,
                                const int* __restrict__ angm, const int* __restrict__ bondm,
                                const int* __restrict__ mask_angle, const int* __restrict__ aa,
                                const float* __restrict__ ang_w1, const float* __restrict__ time_pos,
                                const float* __restrict__ te_w1, const float* __restrict__ te_w2,
                                const float* __restrict__ ang_w2, const float* __restrict__ angproj_w,
                                const float* __restrict__ posproj_w,
                                bf16* __restrict__ Hang, bf16* __restrict__ e,
                                bf16* __restrict__ tw1t, bf16* __restrict__ tw2t,
                                bf16* __restrict__ aw2t, bf16* __restrict__ apjt,
                                bf16* __restrict__ ppjt,
                                unsigned char* __restrict__ amask8, int* __restrict__ teidx,
                                int* __restrict__ seg, int* __restrict__ valid){
  __shared__ float tsh[32][33];
  int blk = blockIdx.x;
  int tid = threadIdx.x;
  if (blk < NB_ANGH){
    // anghid: H[49152,128] = gelu((amask? angle:0) * w1[k])
    size_t idx = (size_t)blk*256 + tid;
    int row = (int)(idx >> 7);
    int k = (int)(idx & 127);
    int b = row / (SEQL*6);
    int rr = row - b*(SEQL*6);
    int l = rr / 6, j = rr - l*6;
    int bl = b*SEQL + l;
    int m = (j<3) ? angm[bl*3+j] : bondm[bl*3+(j-3)];
    float x = m ? angle[bl*6+j] : 0.f;
    Hang[idx] = __float2bfloat16(gelu_f(x * ang_w1[k]));
    return;
  }
  blk -= NB_ANGH;
  if (blk < NB_SIN){
    size_t idx = (size_t)blk*256 + tid;
    int row = (int)(idx >> 9);
    int d = (int)(idx & 511);
    float t = (row < NROWS) ? time_pos[row] : 0.f;
    int k = d & 255;
    float f = expf(-9.210340371976184f * (float)k * (1.0f/256.0f));
    float a = t * f;
    e[idx] = __float2bfloat16((d < 256) ? sinf(a) : cosf(a));
    return;
  }
  blk -= NB_SIN;
  if (blk < NB_TR){
    if (blk < 256)       do_transpose(te_w1, tw1t, 512, blk, tsh);
    else if (blk < 512)  do_transpose(te_w2, tw2t, 512, blk-256, tsh);
    else if (blk < 576)  do_transpose(ang_w2, aw2t, 128, blk-512, tsh);
    else if (blk < 2112) do_transpose(angproj_w, apjt, 3072, blk-576, tsh);
    else                 do_transpose(posproj_w, ppjt, 512, blk-2112, tsh);
    return;
  }
  blk -= NB_TR;
  if (blk < NB_PREP){
    int r = blk*256 + tid;
    int b = r / (SEQL*6);
    int rr = r - b*(SEQL*6);
    int l = rr / 6, j = rr - l*6;
    int bl = b*SEQL + l;
    int am = (j<3) ? angm[bl*3+j] : bondm[bl*3+(j-3)];
    int l2 = rr & (SEQL-1);            // tile(.,(1,6,1)) quirk
    int bl2 = b*SEQL + l2;
    int a2 = aa[bl2];
    int tm = mask_angle[bl2] && (a2!=0) && (a2!=2);
    amask8[r] = (unsigned char)(am != 0);
    teidx[r] = (tm && am) ? bl : T0ROW;
    return;
  }
  // scan: wave w handles batch w
  {
    int b = tid >> 6, lane = tid & 63;
    const int CH = SEQL/64;
    int base = b*SEQL + lane*CH;
    int av[CH];
    int lc=0, le=0;
    #pragma unroll
    for (int i=0;i<CH;i++){ int a=aa[base+i]; av[i]=a; lc += (a==0); le += (a==2); }
    int pc=lc, pe=le;
    #pragma unroll
    for (int off=1; off<64; off<<=1){
      int tc = __shfl_up(pc, off);
      int te = __shfl_up(pe, off);
      if (lane >= off){ pc += tc; pe += te; }
    }
    int c = pc - lc, eo = pe - le;
    #pragma unroll
    for (int i=0;i<CH;i++){
      int a = av[i];
      c += (a==0); eo += (a==2);
      seg[base+i] = c;
      valid[base+i] = (c>eo) && (a!=0) && (a!=2);
    }
  }
}

// ---- per-row mean pairwise distance within segment (one wave per row) ----
__global__ void dist_kernel(const float* __restrict__ pos, const int* __restrict__ seg,
                            const int* __restrict__ valid, float* __restrict__ dist){
  int gw = (int)((blockIdx.x * blockDim.x + threadIdx.x) >> 6);
  int lane = threadIdx.x & 63;
  if (gw >= NROWS) return;
  float out = 0.f;
  if (valid[gw]){
    int b = gw / SEQL;
    int sg = seg[gw];
    float px = pos[(size_t)gw*9+3], py = pos[(size_t)gw*9+4], pz = pos[(size_t)gw*9+5];
    float s = 0.f; int cnt = 0;
    int rowbase = b*SEQL;
    for (int j = lane; j < SEQL; j += 64){
      int idx = rowbase + j;
      if (valid[idx] && seg[idx]==sg){
        float dx = px - pos[(size_t)idx*9+3];
        float dy = py - pos[(size_t)idx*9+4];
        float dz = pz - pos[(size_t)idx*9+5];
        float sq = dx*dx+dy*dy+dz*dz;
        s += (sq>0.f) ? sqrtf(sq) : 0.f;
        cnt += 1;
      }
    }
    #pragma unroll
    for (int off=32; off>0; off>>=1){
      s   += __shfl_down(s, off);
      cnt += __shfl_down(cnt, off);
    }
    out = s / (float)(cnt > 0 ? cnt : 1);
  }
  if (lane==0) dist[gw] = out;
}

// ---- pos feature (bf16): (pos_mask? gelu(dist*w1)*w2 : unkpos) + temb ----
__global__ void posfeat_kernel(const float* __restrict__ dist, const int* __restrict__ aa,
                               const int* __restrict__ mask_angle, const float* __restrict__ pw1,
                               const float* __restrict__ pw2, const float* __restrict__ unkpos,
                               const bf16* __restrict__ E, bf16* __restrict__ PF){
  size_t idx = (size_t)blockIdx.x*256 + threadIdx.x;
  if (idx >= (size_t)NROWS*DDIM) return;
  int row = (int)(idx >> 9);
  int d = (int)(idx & 511);
  int a = aa[row];
  bool ce = (a==0) || (a==2);
  float base = ce ? unkpos[d] : gelu_f(dist[row]*pw1[0]) * pw2[d];
  bool tm = mask_angle[row] && !ce;
  float te = __bfloat162float(E[(size_t)(tm ? row : T0ROW)*DDIM + d]);
  PF[idx] = __float2bfloat16(base + te);
}

// ---- reduce split-K partials + bias + cls/eos/pad -> out[:, :512] ----
__global__ void reduce_final_kernel(const float* __restrict__ P0, const float* __restrict__ P1,
                                    const float* __restrict__ bias, const int* __restrict__ aa,
                                    const int* __restrict__ pad, const float* __restrict__ cls,
                                    const float* __restrict__ eos, float* __restrict__ out){
  int idx = blockIdx.x*256 + threadIdx.x;     // per float4
  if (idx >= NROWS*DDIM/4) return;
  int e0 = idx*4;
  int row = e0 >> 9, col = e0 & 511;
  float4 a = *(const float4*)(P0 + (size_t)row*DDIM + col);
  float4 b = *(const float4*)(P1 + (size_t)row*DDIM + col);
  float4 bi = *(const float4*)(bias + col);
  float4 v = make_float4(a.x+b.x+bi.x, a.y+b.y+bi.y, a.z+b.z+bi.z, a.w+b.w+bi.w);
  int am = aa[row];
  if (am==0) v = *(const float4*)(cls + col);
  else if (am==2) v = *(const float4*)(eos + col);
  if (pad[row]) v = make_float4(0.f,0.f,0.f,0.f);
  *(float4*)(out + (size_t)row*1024 + col) = v;
}

// ================= bf16 MFMA GEMM: C = A[M,K] @ Bt[512,K]^T =================
// 128x128 tile, 512 threads (8 waves 2x4, 64x32 each), 16x16x32 MFMA, BK=32.
// global_load_lds(16B) staging, chunk-XOR swizzle (R2-verified, 0 conflicts).
// EPI: 0 gelu(v+bias)->bf16 | 1 v+bias->bf16 | 2 assemble->bf16
//      3 final(v+bias,overrides)->fp32 | 4 raw fp32 partial (split-K)
// SWZ: 1-D grid 512, XCD co-location: id = (y%8) + 8*(y>>3) + 64*x + 256*z
struct EpiArgs {
  const float* bias;
  const bf16*  E;
  const int*   teidx;
  const unsigned char* amask;
  const float* unk;
  const int*   aa;
  const int*   pad;
  const float* cls;
  const float* eos;
  float*       outF;
  float*       outF2;    // split-K z=1 partial
  bf16*        outB;
  int          ldc;
};

template<int EPI, int SWZ>
__launch_bounds__(512)
__global__ void gemm_bf16(const bf16* __restrict__ A, const bf16* __restrict__ Bt,
                          int K, int kLen, EpiArgs ea){
  __shared__ char Al[128*64];
  __shared__ char Bl[128*64];
  int bx, by, bz = 0;
  if (SWZ){
    int id = blockIdx.x;
    int c = id & 7, rest = id >> 3;
    by = (rest & 7)*8 + c;
    bx = (rest >> 3) & 3;
    bz = rest >> 5;
  } else { bx = blockIdx.x; by = blockIdx.y; }
  const int kBegin = bz * kLen;
  const int tid = threadIdx.x;
  const int w = tid >> 6, lane = tid & 63;
  const int bm = by*128, bn = bx*128;

  // staging: wave w loads rows [16w,16w+16) of A-tile and of B-tile
  const int r = w*16 + (lane>>2);
  const int ch = lane & 3;
  const int cg = ch ^ ((r>>1)&3);
  const char* gA = (const char*)(A  + (size_t)(bm+r)*K + kBegin + cg*8);
  const char* gB = (const char*)(Bt + (size_t)(bn+r)*K + kBegin + cg*8);
  char* lA = Al + w*1024;
  char* lB = Bl + w*1024;

  const int wm = (w>>2)*64, wn = (w&3)*32;
  const int lm = lane & 15, kq = lane >> 4;
  const int sw = kq ^ ((lm>>1)&3);

  f32x4 acc[4][2];
  #pragma unroll
  for (int i=0;i<4;i++)
    #pragma unroll
    for (int j=0;j<2;j++) acc[i][j] = (f32x4){0.f,0.f,0.f,0.f};

  for (int k0 = 0; k0 < kLen; k0 += 32){
    gload16(gA + (size_t)k0*2, lA);
    gload16(gB + (size_t)k0*2, lB);
    __syncthreads();
    short8 af[4], bfr[2];
    #pragma unroll
    for (int t=0;t<4;t++) af[t]  = *(const short8*)(Al + (wm+t*16+lm)*64 + sw*16);
    #pragma unroll
    for (int t=0;t<2;t++) bfr[t] = *(const short8*)(Bl + (wn+t*16+lm)*64 + sw*16);
    #pragma unroll
    for (int mt=0;mt<4;mt++)
      #pragma unroll
      for (int nt=0;nt<2;nt++)
        acc[mt][nt] = __builtin_amdgcn_mfma_f32_16x16x32_bf16(af[mt], bfr[nt], acc[mt][nt], 0, 0, 0);
    __syncthreads();
  }

  // epilogue: C/D layout col=lane&15, row=(lane>>4)*4+reg  [m89-verified]
  #pragma unroll
  for (int mt=0;mt<4;mt++){
    #pragma unroll
    for (int rr=0;rr<4;rr++){
      int row = bm + wm + mt*16 + kq*4 + rr;
      #pragma unroll
      for (int nt=0;nt<2;nt++){
        int col = bn + wn + nt*16 + lm;
        float v = acc[mt][nt][rr];
        if (EPI==0){
          ea.outB[(size_t)row*ea.ldc + col] = __float2bfloat16(gelu_f(v + ea.bias[col]));
        } else if (EPI==1){
          ea.outB[(size_t)row*ea.ldc + col] = __float2bfloat16(v + ea.bias[col]);
        } else if (EPI==2){
          float v2 = ea.amask[row] ? v : ea.unk[col];
          v2 += __bfloat162float(ea.E[(size_t)ea.teidx[row]*DDIM + col]);
          ea.outB[(size_t)row*ea.ldc + col] = __float2bfloat16(v2);
        } else if (EPI==3){
          float v2 = v + ea.bias[col];
          int a = ea.aa[row];
          if (a==0) v2 = ea.cls[col];
          else if (a==2) v2 = ea.eos[col];
          if (ea.pad[row]) v2 = 0.f;
          ea.outF[(size_t)row*ea.ldc + col] = v2;
        } else {
          float* P = bz ? ea.outF2 : ea.outF;
          P[(size_t)row*DDIM + col] = v;
        }
      }
    }
  }
}

extern "C" void kernel_launch(void* const* d_in, const int* in_sizes, int n_in,
                              void* d_out, int out_size, void* d_ws, size_t ws_size,
                              hipStream_t stream){
  const float* pos        = (const float*)d_in[0];
  const float* angle      = (const float*)d_in[1];
  const int*   padm       = (const int*)d_in[2];
  const int*   mask_angle = (const int*)d_in[5];
  const int*   angle_mask = (const int*)d_in[6];
  const int*   bond_mask  = (const int*)d_in[7];
  const float* time_pos   = (const float*)d_in[8];
  const int*   aa         = (const int*)d_in[10];
  const float* ang_w1     = (const float*)d_in[11];
  const float* ang_w2     = (const float*)d_in[12];
  const float* pos_w1     = (const float*)d_in[13];
  const float* pos_w2     = (const float*)d_in[14];
  const float* te_w1      = (const float*)d_in[15];
  const float* te_b1      = (const float*)d_in[16];
  const float* te_w2      = (const float*)d_in[17];
  const float* te_b2      = (const float*)d_in[18];
  const float* angproj_w  = (const float*)d_in[19];
  const float* angproj_b  = (const float*)d_in[20];
  const float* posproj_w  = (const float*)d_in[21];
  const float* posproj_b  = (const float*)d_in[22];
  const float* cls_w      = (const float*)d_in[23];
  const float* eos_w      = (const float*)d_in[24];
  const float* unkang     = (const float*)d_in[25];
  const float* unkpos     = (const float*)d_in[26];

  char* ws = (char*)d_ws;
  size_t off = 0;
  auto alloc = [&](size_t bytes)->char*{
    char* p = ws + off;
    off += (bytes + 255) & ~(size_t)255;
    return p;
  };
  int*   seg    = (int*)  alloc((size_t)NROWS*4);
  int*   valid  = (int*)  alloc((size_t)NROWS*4);
  float* dist   = (float*)alloc((size_t)NROWS*4);
  unsigned char* amask8 = (unsigned char*)alloc(NANG);
  int*   teidx  = (int*)  alloc((size_t)NANG*4);
  bf16*  e      = (bf16*) alloc((size_t)MTE*DDIM*2);
  bf16*  H1     = (bf16*) alloc((size_t)MTE*DDIM*2);
  bf16*  E      = (bf16*) alloc((size_t)MTE*DDIM*2);
  bf16*  Hang   = (bf16*) alloc((size_t)NANG*AHID*2);
  bf16*  AF     = (bf16*) alloc((size_t)NANG*DDIM*2);
  bf16*  PF     = (bf16*) alloc((size_t)NROWS*DDIM*2);
  bf16*  tw1t   = (bf16*) alloc((size_t)DDIM*DDIM*2);
  bf16*  tw2t   = (bf16*) alloc((size_t)DDIM*DDIM*2);
  bf16*  aw2t   = (bf16*) alloc((size_t)DDIM*AHID*2);
  bf16*  apjt   = (bf16*) alloc((size_t)DDIM*6*DDIM*2);
  bf16*  ppjt   = (bf16*) alloc((size_t)DDIM*DDIM*2);
  float* P0     = (float*)alloc((size_t)NROWS*DDIM*4);
  float* P1     = (float*)alloc((size_t)NROWS*DDIM*4);

  float* out = (float*)d_out;
  dim3 b256(256), b512(512);

  // 1. prologue: anghid + sinemb + transposes + prep_ang + scan (one launch)
  prologue_kernel<<<dim3(NB_TOTAL), b256, 0, stream>>>(
      angle, angle_mask, bond_mask, mask_angle, aa, ang_w1, time_pos,
      te_w1, te_w2, ang_w2, angproj_w, posproj_w,
      Hang, e, tw1t, tw2t, aw2t, apjt, ppjt, amask8, teidx, seg, valid);

  // 2. distances (needs scan)
  dist_kernel<<<dim3(NROWS/4), b256, 0, stream>>>(pos, seg, valid, dist);

  // 3. time-embedding MLP (8320 rows incl. t0)
  EpiArgs ea{};
  ea.bias = te_b1; ea.outB = H1; ea.ldc = DDIM;
  gemm_bf16<0,0><<<dim3(4, MTE/128), b512, 0, stream>>>(e, tw1t, DDIM, DDIM, ea);
  ea.bias = te_b2; ea.outB = E;
  gemm_bf16<1,0><<<dim3(4, MTE/128), b512, 0, stream>>>(H1, tw2t, DDIM, DDIM, ea);

  // 4. angle base GEMM with fused assemble epilogue -> AF bf16 [49152,512]
  EpiArgs ea2{};
  ea2.E = E; ea2.teidx = teidx; ea2.amask = amask8; ea2.unk = unkang;
  ea2.outB = AF; ea2.ldc = DDIM;
  gemm_bf16<2,0><<<dim3(4, NANG/128), b512, 0, stream>>>(Hang, aw2t, AHID, AHID, ea2);

  // 5. angle projection [8192,3072]@[3072,512], split-K=2, XCD-swizzled
  EpiArgs ea3{};
  ea3.outF = P0; ea3.outF2 = P1;
  gemm_bf16<4,1><<<dim3(512), b512, 0, stream>>>(AF, apjt, 6*DDIM, 3*DDIM, ea3);

  // 6. pos feature + projection with fused finalize -> out[:, 512:]
  posfeat_kernel<<<dim3((NROWS*DDIM)/256), b256, 0, stream>>>(dist, aa, mask_angle, pos_w1, pos_w2, unkpos, E, PF);
  EpiArgs ea4{};
  ea4.bias = posproj_b; ea4.aa = aa; ea4.pad = padm; ea4.cls = cls_w + DDIM; ea4.eos = eos_w + DDIM;
  ea4.outF = out + DDIM; ea4.ldc = 1024;
  gemm_bf16<3,0><<<dim3(4, NROWS/128), b512, 0, stream>>>(PF, ppjt, DDIM, DDIM, ea4);

  // 7. reduce split-K partials + bias + overrides -> out[:, :512]
  reduce_final_kernel<<<dim3(NROWS*DDIM/4/256), b256, 0, stream>>>(
      P0, P1, angproj_b, aa, padm, cls_w, eos_w, out);
}

// Round 5
// 279.930 us; speedup vs baseline: 4.2372x; 1.1569x over previous
//
#include <hip/hip_runtime.h>
#include <hip/hip_bf16.h>
#include <cstdint>
#include <cstddef>

#define BSZ 4
#define SEQL 2048
#define DDIM 512
#define AHID 128
#define NROWS (BSZ*SEQL)        // 8192
#define MTE 8320                // 8192 rows + t0 rows, padded to 128
#define T0ROW 8192
#define NANG (NROWS*6)          // 49152

typedef __attribute__((ext_vector_type(8))) short short8;
typedef __attribute__((ext_vector_type(4))) float f32x4;
typedef __hip_bfloat16 bf16;

__device__ __forceinline__ float gelu_f(float x){
  return 0.5f * x * (1.0f + erff(x * 0.7071067811865475f));
}

__device__ __forceinline__ void gload16(const void* g, void* l){
  __builtin_amdgcn_global_load_lds(
      (const __attribute__((address_space(1))) unsigned int*)g,
      (__attribute__((address_space(3))) unsigned int*)l,
      16, 0, 0);
}

__device__ __forceinline__ unsigned int packbf2(float a, float b){
  __hip_bfloat16 ha = __float2bfloat16(a), hb = __float2bfloat16(b);
  return (unsigned int)(*(unsigned short*)&ha) | ((unsigned int)(*(unsigned short*)&hb) << 16);
}
__device__ __forceinline__ float bflo(unsigned int u){
  union{unsigned int i; float f;} x; x.i = u << 16; return x.f;
}
__device__ __forceinline__ float bfhi(unsigned int u){
  union{unsigned int i; float f;} x; x.i = u & 0xffff0000u; return x.f;
}

// ====================== scan: 1 block, wave per batch ======================
__global__ void scan_kernel(const int* __restrict__ aa, int* __restrict__ seg,
                            int* __restrict__ valid){
  int b = threadIdx.x >> 6, lane = threadIdx.x & 63;
  const int CH = SEQL/64;
  int base = b*SEQL + lane*CH;
  int av[CH];
  int lc=0, le=0;
  #pragma unroll
  for (int i=0;i<CH;i++){ int a=aa[base+i]; av[i]=a; lc += (a==0); le += (a==2); }
  int pc=lc, pe=le;
  #pragma unroll
  for (int off=1; off<64; off<<=1){
    int tc = __shfl_up(pc, off);
    int te = __shfl_up(pe, off);
    if (lane >= off){ pc += tc; pe += te; }
  }
  int c = pc - lc, eo = pe - le;
  #pragma unroll
  for (int i=0;i<CH;i++){
    int a = av[i];
    c += (a==0); eo += (a==2);
    seg[base+i] = c;
    valid[base+i] = (c>eo) && (a!=0) && (a!=2);
  }
}

// ====================== prologue mega-kernel ======================
#define NB_ANGH 3072    // NANG*AHID/8/256
#define NB_SIN  2080    // MTE*DDIM/8/256
#define NB_TR   2368    // 256+256+64+1536+256
#define NB_PREP 192     // NANG/256
#define NB_PK   32      // NROWS/256
#define NB_TOTAL (NB_ANGH+NB_SIN+NB_TR+NB_PREP+NB_PK)

__device__ void do_transpose(const float* __restrict__ W, bf16* __restrict__ Wt,
                             int K, int q, float (*tsh)[33]){
  int k0 = (q >> 4)*32, n0 = (q & 15)*32;
  int tx = threadIdx.x & 31, ty = threadIdx.x >> 5;
  #pragma unroll
  for (int i=0;i<32;i+=8)
    tsh[ty+i][tx] = W[(size_t)(k0+ty+i)*512 + n0+tx];
  __syncthreads();
  #pragma unroll
  for (int i=0;i<32;i+=8)
    Wt[(size_t)(n0+ty+i)*K + k0+tx] = __float2bfloat16(tsh[tx][ty+i]);
}

__global__ void prologue_kernel(const float* __restrict__ pos, const float* __restrict__ angle,
                                const int* __restrict__ angm, const int* __restrict__ bondm,
                                const int* __restrict__ mask_angle, const int* __restrict__ aa,
                                const float* __restrict__ ang_w1, const float* __restrict__ time_pos,
                                const float* __restrict__ te_w1, const float* __restrict__ te_w2,
                                const float* __restrict__ ang_w2, const float* __restrict__ angproj_w,
                                const float* __restrict__ posproj_w,
                                const int* __restrict__ seg, const int* __restrict__ valid,
                                bf16* __restrict__ Hang, bf16* __restrict__ e,
                                bf16* __restrict__ tw1t, bf16* __restrict__ tw2t,
                                bf16* __restrict__ aw2t, bf16* __restrict__ apjt,
                                bf16* __restrict__ ppjt,
                                unsigned char* __restrict__ amask8, int* __restrict__ teidx,
                                float4* __restrict__ pk){
  __shared__ float tsh[32][33];
  int blk = blockIdx.x;
  int tid = threadIdx.x;
  if (blk < NB_ANGH){
    // anghid x8: H[49152,128] = gelu((amask? angle:0) * w1[k])
    int gidx = blk*256 + tid;
    int row = gidx >> 4;
    int kb = (gidx & 15) * 8;
    int b = row / (SEQL*6);
    int rr = row - b*(SEQL*6);
    int l = rr / 6, j = rr - l*6;
    int bl = b*SEQL + l;
    int m = (j<3) ? angm[bl*3+j] : bondm[bl*3+(j-3)];
    float x = m ? angle[bl*6+j] : 0.f;
    float4 w0 = *(const float4*)(ang_w1+kb);
    float4 w1v = *(const float4*)(ang_w1+kb+4);
    uint4 st;
    st.x = packbf2(gelu_f(x*w0.x),  gelu_f(x*w0.y));
    st.y = packbf2(gelu_f(x*w0.z),  gelu_f(x*w0.w));
    st.z = packbf2(gelu_f(x*w1v.x), gelu_f(x*w1v.y));
    st.w = packbf2(gelu_f(x*w1v.z), gelu_f(x*w1v.w));
    *(uint4*)(Hang + (size_t)row*AHID + kb) = st;
    return;
  }
  blk -= NB_ANGH;
  if (blk < NB_SIN){
    int gidx = blk*256 + tid;
    int row = gidx >> 6;
    int db = (gidx & 63) * 8;
    float t = (row < NROWS) ? time_pos[row] : 0.f;
    float v[8];
    #pragma unroll
    for (int i=0;i<8;i++){
      int d = db + i;
      int k = d & 255;
      float f = expf(-0.035977892078f * (float)k);
      float a = t * f;
      v[i] = (d < 256) ? sinf(a) : cosf(a);
    }
    uint4 st;
    st.x = packbf2(v[0],v[1]); st.y = packbf2(v[2],v[3]);
    st.z = packbf2(v[4],v[5]); st.w = packbf2(v[6],v[7]);
    *(uint4*)(e + (size_t)row*DDIM + db) = st;
    return;
  }
  blk -= NB_SIN;
  if (blk < NB_TR){
    if (blk < 256)       do_transpose(te_w1, tw1t, 512, blk, tsh);
    else if (blk < 512)  do_transpose(te_w2, tw2t, 512, blk-256, tsh);
    else if (blk < 576)  do_transpose(ang_w2, aw2t, 128, blk-512, tsh);
    else if (blk < 2112) do_transpose(angproj_w, apjt, 3072, blk-576, tsh);
    else                 do_transpose(posproj_w, ppjt, 512, blk-2112, tsh);
    return;
  }
  blk -= NB_TR;
  if (blk < NB_PREP){
    int r = blk*256 + tid;
    int b = r / (SEQL*6);
    int rr = r - b*(SEQL*6);
    int l = rr / 6, j = rr - l*6;
    int bl = b*SEQL + l;
    int am = (j<3) ? angm[bl*3+j] : bondm[bl*3+(j-3)];
    int l2 = rr & (SEQL-1);            // tile(.,(1,6,1)) quirk
    int bl2 = b*SEQL + l2;
    int a2 = aa[bl2];
    int tm = mask_angle[bl2] && (a2!=0) && (a2!=2);
    amask8[r] = (unsigned char)(am != 0);
    teidx[r] = (tm && am) ? bl : T0ROW;
    return;
  }
  blk -= NB_PREP;
  {
    int i = blk*256 + tid;             // packed dist input
    float4 q;
    q.x = pos[(size_t)i*9+3];
    q.y = pos[(size_t)i*9+4];
    q.z = pos[(size_t)i*9+5];
    q.w = valid[i] ? (float)seg[i] : -1.f;
    pk[i] = q;
  }
}

// ---- per-row mean pairwise distance within segment (one wave per row) ----
__global__ void dist_kernel(const float4* __restrict__ pk, float* __restrict__ dist){
  int gw = (int)((blockIdx.x * blockDim.x + threadIdx.x) >> 6);
  int lane = threadIdx.x & 63;
  if (gw >= NROWS) return;
  float4 c = pk[gw];
  float out = 0.f;
  if (c.w >= 0.f){
    int rowbase = (gw >> 11) << 11;
    float s = 0.f, cnt = 0.f;
    for (int j = lane; j < SEQL; j += 64){
      float4 q = pk[rowbase + j];
      if (q.w == c.w){
        float dx = c.x-q.x, dy = c.y-q.y, dz = c.z-q.z;
        float sq = dx*dx+dy*dy+dz*dz;
        s += (sq>0.f) ? sqrtf(sq) : 0.f;
        cnt += 1.f;
      }
    }
    #pragma unroll
    for (int off=32; off>0; off>>=1){
      s   += __shfl_down(s, off);
      cnt += __shfl_down(cnt, off);
    }
    out = s / fmaxf(cnt, 1.f);
  }
  if (lane==0) dist[gw] = out;
}

// ---- pos feature x8 (bf16): (pos_mask? gelu(dist*w1)*w2 : unkpos) + temb ----
__global__ void posfeat_kernel(const float* __restrict__ dist, const int* __restrict__ aa,
                               const int* __restrict__ mask_angle, const float* __restrict__ pw1,
                               const float* __restrict__ pw2, const float* __restrict__ unkpos,
                               const bf16* __restrict__ E, bf16* __restrict__ PF){
  int gidx = blockIdx.x*256 + threadIdx.x;
  int row = gidx >> 6;
  int db = (gidx & 63) * 8;
  int a = aa[row];
  bool ce = (a==0) || (a==2);
  float g = ce ? 0.f : gelu_f(dist[row]*pw1[0]);
  bool tm = mask_angle[row] && !ce;
  uint4 ev = *(const uint4*)(E + (size_t)(tm ? row : T0ROW)*DDIM + db);
  float te[8] = {bflo(ev.x),bfhi(ev.x),bflo(ev.y),bfhi(ev.y),bflo(ev.z),bfhi(ev.z),bflo(ev.w),bfhi(ev.w)};
  float bsv[8];
  if (ce){
    float4 u0 = *(const float4*)(unkpos+db), u1 = *(const float4*)(unkpos+db+4);
    bsv[0]=u0.x;bsv[1]=u0.y;bsv[2]=u0.z;bsv[3]=u0.w;bsv[4]=u1.x;bsv[5]=u1.y;bsv[6]=u1.z;bsv[7]=u1.w;
  } else {
    float4 w0 = *(const float4*)(pw2+db), w1 = *(const float4*)(pw2+db+4);
    bsv[0]=g*w0.x;bsv[1]=g*w0.y;bsv[2]=g*w0.z;bsv[3]=g*w0.w;bsv[4]=g*w1.x;bsv[5]=g*w1.y;bsv[6]=g*w1.z;bsv[7]=g*w1.w;
  }
  uint4 st;
  st.x = packbf2(bsv[0]+te[0], bsv[1]+te[1]);
  st.y = packbf2(bsv[2]+te[2], bsv[3]+te[3]);
  st.z = packbf2(bsv[4]+te[4], bsv[5]+te[5]);
  st.w = packbf2(bsv[6]+te[6], bsv[7]+te[7]);
  *(uint4*)(PF + (size_t)row*DDIM + db) = st;
}

// ---- reduce split-K partials x8 + bias + cls/eos/pad -> out[:, :512] ----
__global__ void reduce_final_kernel(const float* __restrict__ P0, const float* __restrict__ P1,
                                    const float* __restrict__ bias, const int* __restrict__ aa,
                                    const int* __restrict__ pad, const float* __restrict__ cls,
                                    const float* __restrict__ eos, float* __restrict__ out){
  int idx = blockIdx.x*256 + threadIdx.x;     // per 8 floats
  int e0 = idx*8;
  int row = e0 >> 9, col = e0 & 511;
  float v[8];
  {
    float4 a0 = *(const float4*)(P0 + (size_t)row*DDIM + col);
    float4 a1 = *(const float4*)(P0 + (size_t)row*DDIM + col + 4);
    float4 b0 = *(const float4*)(P1 + (size_t)row*DDIM + col);
    float4 b1 = *(const float4*)(P1 + (size_t)row*DDIM + col + 4);
    float4 c0 = *(const float4*)(bias + col);
    float4 c1 = *(const float4*)(bias + col + 4);
    v[0]=a0.x+b0.x+c0.x; v[1]=a0.y+b0.y+c0.y; v[2]=a0.z+b0.z+c0.z; v[3]=a0.w+b0.w+c0.w;
    v[4]=a1.x+b1.x+c1.x; v[5]=a1.y+b1.y+c1.y; v[6]=a1.z+b1.z+c1.z; v[7]=a1.w+b1.w+c1.w;
  }
  int am = aa[row];
  if (am==0){
    float4 c0 = *(const float4*)(cls+col), c1 = *(const float4*)(cls+col+4);
    v[0]=c0.x;v[1]=c0.y;v[2]=c0.z;v[3]=c0.w;v[4]=c1.x;v[5]=c1.y;v[6]=c1.z;v[7]=c1.w;
  } else if (am==2){
    float4 c0 = *(const float4*)(eos+col), c1 = *(const float4*)(eos+col+4);
    v[0]=c0.x;v[1]=c0.y;v[2]=c0.z;v[3]=c0.w;v[4]=c1.x;v[5]=c1.y;v[6]=c1.z;v[7]=c1.w;
  }
  if (pad[row]){
    #pragma unroll
    for (int i=0;i<8;i++) v[i]=0.f;
  }
  *(float4*)(out + (size_t)row*1024 + col)     = make_float4(v[0],v[1],v[2],v[3]);
  *(float4*)(out + (size_t)row*1024 + col + 4) = make_float4(v[4],v[5],v[6],v[7]);
}

// ================= bf16 MFMA GEMM: C = A[M,K] @ Bt[512,K]^T =================
// 128x128 tile, 512 threads (8 waves 2x4, 64x32 each), 16x16x32 MFMA, BK=32.
// global_load_lds(16B) staging, chunk-XOR swizzle (0 conflicts, R2-verified).
// Epilogue: LDS-transpose (stride 36 = 2-way banks, free) -> lane owns
// (row, 8 consecutive cols) -> 16B vector stores/gathers.
// EPI: 0 gelu(v+bias)->bf16 | 1 v+bias->bf16 | 2 assemble->bf16
//      3 final(v+bias,overrides)->fp32 | 4 raw fp32 partial (split-K)
struct EpiArgs {
  const float* bias;
  const bf16*  E;
  const int*   teidx;
  const unsigned char* amask;
  const float* unk;
  const int*   aa;
  const int*   pad;
  const float* cls;
  const float* eos;
  float*       outF;
  float*       outF2;    // split-K z=1 partial
  bf16*        outB;
  int          ldc;
};

template<int EPI, int SWZ>
__launch_bounds__(512)
__global__ void gemm_bf16(const bf16* __restrict__ A, const bf16* __restrict__ Bt,
                          int K, int kLen, EpiArgs ea){
  __shared__ __align__(16) char smem[18432];
  char* Al = smem;
  char* Bl = smem + 8192;
  int bx, by, bz = 0;
  if (SWZ){
    int id = blockIdx.x;
    int c = id & 7, rest = id >> 3;
    by = (rest & 7)*8 + c;
    bx = (rest >> 3) & 3;
    bz = rest >> 5;
  } else { bx = blockIdx.x; by = blockIdx.y; }
  const int kBegin = bz * kLen;
  const int tid = threadIdx.x;
  const int w = tid >> 6, lane = tid & 63;
  const int bm = by*128, bn = bx*128;

  const int r = w*16 + (lane>>2);
  const int ch = lane & 3;
  const int cg = ch ^ ((r>>1)&3);
  const char* gA = (const char*)(A  + (size_t)(bm+r)*K + kBegin + cg*8);
  const char* gB = (const char*)(Bt + (size_t)(bn+r)*K + kBegin + cg*8);
  char* lA = Al + w*1024;
  char* lB = Bl + w*1024;

  const int wm = (w>>2)*64, wn = (w&3)*32;
  const int lm = lane & 15, kq = lane >> 4;
  const int sw = kq ^ ((lm>>1)&3);

  f32x4 acc[4][2];
  #pragma unroll
  for (int i=0;i<4;i++)
    #pragma unroll
    for (int j=0;j<2;j++) acc[i][j] = (f32x4){0.f,0.f,0.f,0.f};

  for (int k0 = 0; k0 < kLen; k0 += 32){
    gload16(gA + (size_t)k0*2, lA);
    gload16(gB + (size_t)k0*2, lB);
    __syncthreads();
    short8 af[4], bfr[2];
    #pragma unroll
    for (int t=0;t<4;t++) af[t]  = *(const short8*)(Al + (wm+t*16+lm)*64 + sw*16);
    #pragma unroll
    for (int t=0;t<2;t++) bfr[t] = *(const short8*)(Bl + (wn+t*16+lm)*64 + sw*16);
    #pragma unroll
    for (int mt=0;mt<4;mt++)
      #pragma unroll
      for (int nt=0;nt<2;nt++)
        acc[mt][nt] = __builtin_amdgcn_mfma_f32_16x16x32_bf16(af[mt], bfr[nt], acc[mt][nt], 0, 0, 0);
    __syncthreads();
  }

  // ---- LDS-transpose epilogue ----
  float* eps = (float*)smem + w*576;     // 16 rows x 36 f32 per wave
  const int erow = lane >> 2;
  const int ecg  = (lane & 3) * 8;
  #pragma unroll
  for (int mt=0; mt<4; mt++){
    if (mt) __syncthreads();             // WAR: prior reads done before rewrite
    #pragma unroll
    for (int nt=0; nt<2; nt++)
      #pragma unroll
      for (int rr=0; rr<4; rr++)
        eps[(kq*4+rr)*36 + nt*16 + lm] = acc[mt][nt][rr];
    __asm__ volatile("s_waitcnt lgkmcnt(0)" ::: "memory");
    float4 t0 = *(float4*)(eps + erow*36 + ecg);
    float4 t1 = *(float4*)(eps + erow*36 + ecg + 4);
    float v[8] = {t0.x,t0.y,t0.z,t0.w,t1.x,t1.y,t1.z,t1.w};
    int row = bm + wm + mt*16 + erow;
    int col = bn + wn + ecg;

    if (EPI==0 || EPI==1){
      float4 b0 = *(const float4*)(ea.bias+col), b1 = *(const float4*)(ea.bias+col+4);
      float bb[8] = {b0.x,b0.y,b0.z,b0.w,b1.x,b1.y,b1.z,b1.w};
      #pragma unroll
      for (int i=0;i<8;i++){
        v[i] += bb[i];
        if (EPI==0) v[i] = gelu_f(v[i]);
      }
      uint4 st;
      st.x = packbf2(v[0],v[1]); st.y = packbf2(v[2],v[3]);
      st.z = packbf2(v[4],v[5]); st.w = packbf2(v[6],v[7]);
      *(uint4*)(ea.outB + (size_t)row*ea.ldc + col) = st;
    } else if (EPI==2){
      if (!ea.amask[row]){
        float4 u0 = *(const float4*)(ea.unk+col), u1 = *(const float4*)(ea.unk+col+4);
        v[0]=u0.x;v[1]=u0.y;v[2]=u0.z;v[3]=u0.w;v[4]=u1.x;v[5]=u1.y;v[6]=u1.z;v[7]=u1.w;
      }
      uint4 evv = *(const uint4*)(ea.E + (size_t)ea.teidx[row]*DDIM + col);
      v[0]+=bflo(evv.x); v[1]+=bfhi(evv.x); v[2]+=bflo(evv.y); v[3]+=bfhi(evv.y);
      v[4]+=bflo(evv.z); v[5]+=bfhi(evv.z); v[6]+=bflo(evv.w); v[7]+=bfhi(evv.w);
      uint4 st;
      st.x = packbf2(v[0],v[1]); st.y = packbf2(v[2],v[3]);
      st.z = packbf2(v[4],v[5]); st.w = packbf2(v[6],v[7]);
      *(uint4*)(ea.outB + (size_t)row*ea.ldc + col) = st;
    } else if (EPI==3){
      float4 b0 = *(const float4*)(ea.bias+col), b1 = *(const float4*)(ea.bias+col+4);
      v[0]+=b0.x; v[1]+=b0.y; v[2]+=b0.z; v[3]+=b0.w;
      v[4]+=b1.x; v[5]+=b1.y; v[6]+=b1.z; v[7]+=b1.w;
      int a = ea.aa[row];
      if (a==0){
        float4 c0 = *(const float4*)(ea.cls+col), c1 = *(const float4*)(ea.cls+col+4);
        v[0]=c0.x;v[1]=c0.y;v[2]=c0.z;v[3]=c0.w;v[4]=c1.x;v[5]=c1.y;v[6]=c1.z;v[7]=c1.w;
      } else if (a==2){
        float4 c0 = *(const float4*)(ea.eos+col), c1 = *(const float4*)(ea.eos+col+4);
        v[0]=c0.x;v[1]=c0.y;v[2]=c0.z;v[3]=c0.w;v[4]=c1.x;v[5]=c1.y;v[6]=c1.z;v[7]=c1.w;
      }
      if (ea.pad[row]){
        #pragma unroll
        for (int i=0;i<8;i++) v[i]=0.f;
      }
      *(float4*)(ea.outF + (size_t)row*ea.ldc + col)     = make_float4(v[0],v[1],v[2],v[3]);
      *(float4*)(ea.outF + (size_t)row*ea.ldc + col + 4) = make_float4(v[4],v[5],v[6],v[7]);
    } else {
      float* P = bz ? ea.outF2 : ea.outF;
      *(float4*)(P + (size_t)row*DDIM + col)     = make_float4(v[0],v[1],v[2],v[3]);
      *(float4*)(P + (size_t)row*DDIM + col + 4) = make_float4(v[4],v[5],v[6],v[7]);
    }
  }
}

extern "C" void kernel_launch(void* const* d_in, const int* in_sizes, int n_in,
                              void* d_out, int out_size, void* d_ws, size_t ws_size,
                              hipStream_t stream){
  const float* pos        = (const float*)d_in[0];
  const float* angle      = (const float*)d_in[1];
  const int*   padm       = (const int*)d_in[2];
  const int*   mask_angle = (const int*)d_in[5];
  const int*   angle_mask = (const int*)d_in[6];
  const int*   bond_mask  = (const int*)d_in[7];
  const float* time_pos   = (const float*)d_in[8];
  const int*   aa         = (const int*)d_in[10];
  const float* ang_w1     = (const float*)d_in[11];
  const float* ang_w2     = (const float*)d_in[12];
  const float* pos_w1     = (const float*)d_in[13];
  const float* pos_w2     = (const float*)d_in[14];
  const float* te_w1      = (const float*)d_in[15];
  const float* te_b1      = (const float*)d_in[16];
  const float* te_w2      = (const float*)d_in[17];
  const float* te_b2      = (const float*)d_in[18];
  const float* angproj_w  = (const float*)d_in[19];
  const float* angproj_b  = (const float*)d_in[20];
  const float* posproj_w  = (const float*)d_in[21];
  const float* posproj_b  = (const float*)d_in[22];
  const float* cls_w      = (const float*)d_in[23];
  const float* eos_w      = (const float*)d_in[24];
  const float* unkang     = (const float*)d_in[25];
  const float* unkpos     = (const float*)d_in[26];

  char* ws = (char*)d_ws;
  size_t off = 0;
  auto alloc = [&](size_t bytes)->char*{
    char* p = ws + off;
    off += (bytes + 255) & ~(size_t)255;
    return p;
  };
  int*   seg    = (int*)  alloc((size_t)NROWS*4);
  int*   valid  = (int*)  alloc((size_t)NROWS*4);
  float* dist   = (float*)alloc((size_t)NROWS*4);
  float4* pk    = (float4*)alloc((size_t)NROWS*16);
  unsigned char* amask8 = (unsigned char*)alloc(NANG);
  int*   teidx  = (int*)  alloc((size_t)NANG*4);
  bf16*  e      = (bf16*) alloc((size_t)MTE*DDIM*2);
  bf16*  H1     = (bf16*) alloc((size_t)MTE*DDIM*2);
  bf16*  E      = (bf16*) alloc((size_t)MTE*DDIM*2);
  bf16*  Hang   = (bf16*) alloc((size_t)NANG*AHID*2);
  bf16*  AF     = (bf16*) alloc((size_t)NANG*DDIM*2);
  bf16*  PF     = (bf16*) alloc((size_t)NROWS*DDIM*2);
  bf16*  tw1t   = (bf16*) alloc((size_t)DDIM*DDIM*2);
  bf16*  tw2t   = (bf16*) alloc((size_t)DDIM*DDIM*2);
  bf16*  aw2t   = (bf16*) alloc((size_t)DDIM*AHID*2);
  bf16*  apjt   = (bf16*) alloc((size_t)DDIM*6*DDIM*2);
  bf16*  ppjt   = (bf16*) alloc((size_t)DDIM*DDIM*2);
  float* P0     = (float*)alloc((size_t)NROWS*DDIM*4);
  float* P1     = (float*)alloc((size_t)NROWS*DDIM*4);

  float* out = (float*)d_out;
  dim3 b256(256), b512(512);

  // 1. scan (tiny), then prologue: anghid+sinemb+transposes+prep+pk
  scan_kernel<<<dim3(1), b256, 0, stream>>>(aa, seg, valid);
  prologue_kernel<<<dim3(NB_TOTAL), b256, 0, stream>>>(
      pos, angle, angle_mask, bond_mask, mask_angle, aa, ang_w1, time_pos,
      te_w1, te_w2, ang_w2, angproj_w, posproj_w, seg, valid,
      Hang, e, tw1t, tw2t, aw2t, apjt, ppjt, amask8, teidx, pk);

  // 2. distances
  dist_kernel<<<dim3(NROWS/4), b256, 0, stream>>>(pk, dist);

  // 3. time-embedding MLP (8320 rows incl. t0)
  EpiArgs ea{};
  ea.bias = te_b1; ea.outB = H1; ea.ldc = DDIM;
  gemm_bf16<0,0><<<dim3(4, MTE/128), b512, 0, stream>>>(e, tw1t, DDIM, DDIM, ea);
  ea.bias = te_b2; ea.outB = E;
  gemm_bf16<1,0><<<dim3(4, MTE/128), b512, 0, stream>>>(H1, tw2t, DDIM, DDIM, ea);

  // 4. angle base GEMM + fused assemble -> AF bf16 [49152,512]
  EpiArgs ea2{};
  ea2.E = E; ea2.teidx = teidx; ea2.amask = amask8; ea2.unk = unkang;
  ea2.outB = AF; ea2.ldc = DDIM;
  gemm_bf16<2,0><<<dim3(4, NANG/128), b512, 0, stream>>>(Hang, aw2t, AHID, AHID, ea2);

  // 5. angle projection [8192,3072]@[3072,512], split-K=2, XCD-swizzled
  EpiArgs ea3{};
  ea3.outF = P0; ea3.outF2 = P1;
  gemm_bf16<4,1><<<dim3(512), b512, 0, stream>>>(AF, apjt, 6*DDIM, 3*DDIM, ea3);

  // 6. pos feature + projection with fused finalize -> out[:, 512:]
  posfeat_kernel<<<dim3(NROWS*DDIM/8/256), b256, 0, stream>>>(dist, aa, mask_angle, pos_w1, pos_w2, unkpos, E, PF);
  EpiArgs ea4{};
  ea4.bias = posproj_b; ea4.aa = aa; ea4.pad = padm; ea4.cls = cls_w + DDIM; ea4.eos = eos_w + DDIM;
  ea4.outF = out + DDIM; ea4.ldc = 1024;
  gemm_bf16<3,0><<<dim3(4, NROWS/128), b512, 0, stream>>>(PF, ppjt, DDIM, DDIM, ea4);

  // 7. reduce split-K partials + bias + overrides -> out[:, :512]
  reduce_final_kernel<<<dim3(NROWS*DDIM/8/256), b256, 0, stream>>>(
      P0, P1, angproj_b, aa, padm, cls_w, eos_w, out);
}

// Round 6
// 274.371 us; speedup vs baseline: 4.3231x; 1.0203x over previous
//
#include <hip/hip_runtime.h>
#include <hip/hip_bf16.h>
#include <cstdint>
#include <cstddef>

#define BSZ 4
#define SEQL 2048
#define DDIM 512
#define AHID 128
#define NROWS (BSZ*SEQL)        // 8192
#define MTE 8320                // 8192 rows + t0 rows, padded to 128
#define T0ROW 8192
#define NANG (NROWS*6)          // 49152

typedef __attribute__((ext_vector_type(8))) short short8;
typedef __attribute__((ext_vector_type(4))) float f32x4;
typedef __hip_bfloat16 bf16;

__device__ __forceinline__ float gelu_f(float x){
  return 0.5f * x * (1.0f + erff(x * 0.7071067811865475f));
}

__device__ __forceinline__ void gload16(const void* g, void* l){
  __builtin_amdgcn_global_load_lds(
      (const __attribute__((address_space(1))) unsigned int*)g,
      (__attribute__((address_space(3))) unsigned int*)l,
      16, 0, 0);
}

__device__ __forceinline__ unsigned int packbf2(float a, float b){
  __hip_bfloat16 ha = __float2bfloat16(a), hb = __float2bfloat16(b);
  return (unsigned int)(*(unsigned short*)&ha) | ((unsigned int)(*(unsigned short*)&hb) << 16);
}
__device__ __forceinline__ float bflo(unsigned int u){
  union{unsigned int i; float f;} x; x.i = u << 16; return x.f;
}
__device__ __forceinline__ float bfhi(unsigned int u){
  union{unsigned int i; float f;} x; x.i = u & 0xffff0000u; return x.f;
}

// ============ scan + pack: 1 block; wave b scans batch b, then packs pk ====
__global__ void scan_pack_kernel(const int* __restrict__ aa, const float* __restrict__ pos,
                                 float4* __restrict__ pk){
  int b = threadIdx.x >> 6, lane = threadIdx.x & 63;
  const int CH = SEQL/64;
  int base = b*SEQL + lane*CH;
  int av[CH];
  int lc=0, le=0;
  #pragma unroll
  for (int i=0;i<CH;i++){ int a=aa[base+i]; av[i]=a; lc += (a==0); le += (a==2); }
  int pc=lc, pe=le;
  #pragma unroll
  for (int off=1; off<64; off<<=1){
    int tc = __shfl_up(pc, off);
    int te = __shfl_up(pe, off);
    if (lane >= off){ pc += tc; pe += te; }
  }
  int c = pc - lc, eo = pe - le;
  #pragma unroll
  for (int i=0;i<CH;i++){
    int a = av[i];
    c += (a==0); eo += (a==2);
    bool valid = (c>eo) && (a!=0) && (a!=2);
    float4 q;
    q.x = pos[(size_t)(base+i)*9+3];
    q.y = pos[(size_t)(base+i)*9+4];
    q.z = pos[(size_t)(base+i)*9+5];
    q.w = valid ? (float)c : -1.f;
    pk[base+i] = q;
  }
}

// ====================== prologue mega-kernel (256 thr) ======================
#define NB_ANGH 3072    // NANG*AHID/8/256
#define NB_SIN  2080    // MTE*DDIM/8/256
#define NB_TR   2368    // 256+256+64+1536+256
#define NB_PREP 192     // NANG/256
#define NB_DIST 2048    // NROWS/4 (wave per row)
#define NB_TOTAL (NB_ANGH+NB_SIN+NB_TR+NB_PREP+NB_DIST)

__device__ void do_transpose(const float* __restrict__ W, bf16* __restrict__ Wt,
                             int K, int q, float (*tsh)[33]){
  int k0 = (q >> 4)*32, n0 = (q & 15)*32;
  int tx = threadIdx.x & 31, ty = threadIdx.x >> 5;
  #pragma unroll
  for (int i=0;i<32;i+=8)
    tsh[ty+i][tx] = W[(size_t)(k0+ty+i)*512 + n0+tx];
  __syncthreads();
  #pragma unroll
  for (int i=0;i<32;i+=8)
    Wt[(size_t)(n0+ty+i)*K + k0+tx] = __float2bfloat16(tsh[tx][ty+i]);
}

__global__ void prologue_kernel(const float* __restrict__ angle,
                                const int* __restrict__ angm, const int* __restrict__ bondm,
                                const int* __restrict__ mask_angle, const int* __restrict__ aa,
                                const float* __restrict__ ang_w1, const float* __restrict__ time_pos,
                                const float* __restrict__ te_w1, const float* __restrict__ te_w2,
                                const float* __restrict__ ang_w2, const float* __restrict__ angproj_w,
                                const float* __restrict__ posproj_w,
                                const float4* __restrict__ pk,
                                bf16* __restrict__ Hang, bf16* __restrict__ e,
                                bf16* __restrict__ tw1t, bf16* __restrict__ tw2t,
                                bf16* __restrict__ aw2t, bf16* __restrict__ apjt,
                                bf16* __restrict__ ppjt,
                                unsigned char* __restrict__ amask8, int* __restrict__ teidx,
                                float* __restrict__ dist){
  __shared__ float tsh[32][33];
  int blk = blockIdx.x;
  int tid = threadIdx.x;
  if (blk < NB_ANGH){
    // anghid x8: H[49152,128] = gelu((amask? angle:0) * w1[k])
    int gidx = blk*256 + tid;
    int row = gidx >> 4;
    int kb = (gidx & 15) * 8;
    int b = row / (SEQL*6);
    int rr = row - b*(SEQL*6);
    int l = rr / 6, j = rr - l*6;
    int bl = b*SEQL + l;
    int m = (j<3) ? angm[bl*3+j] : bondm[bl*3+(j-3)];
    float x = m ? angle[bl*6+j] : 0.f;
    float4 w0 = *(const float4*)(ang_w1+kb);
    float4 w1v = *(const float4*)(ang_w1+kb+4);
    uint4 st;
    st.x = packbf2(gelu_f(x*w0.x),  gelu_f(x*w0.y));
    st.y = packbf2(gelu_f(x*w0.z),  gelu_f(x*w0.w));
    st.z = packbf2(gelu_f(x*w1v.x), gelu_f(x*w1v.y));
    st.w = packbf2(gelu_f(x*w1v.z), gelu_f(x*w1v.w));
    *(uint4*)(Hang + (size_t)row*AHID + kb) = st;
    return;
  }
  blk -= NB_ANGH;
  if (blk < NB_SIN){
    int gidx = blk*256 + tid;
    int row = gidx >> 6;
    int db = (gidx & 63) * 8;
    float t = (row < NROWS) ? time_pos[row] : 0.f;
    float v[8];
    #pragma unroll
    for (int i=0;i<8;i++){
      int d = db + i;
      int k = d & 255;
      float f = expf(-0.035977892078f * (float)k);
      float a = t * f;
      v[i] = (d < 256) ? sinf(a) : cosf(a);
    }
    uint4 st;
    st.x = packbf2(v[0],v[1]); st.y = packbf2(v[2],v[3]);
    st.z = packbf2(v[4],v[5]); st.w = packbf2(v[6],v[7]);
    *(uint4*)(e + (size_t)row*DDIM + db) = st;
    return;
  }
  blk -= NB_SIN;
  if (blk < NB_TR){
    if (blk < 256)       do_transpose(te_w1, tw1t, 512, blk, tsh);
    else if (blk < 512)  do_transpose(te_w2, tw2t, 512, blk-256, tsh);
    else if (blk < 576)  do_transpose(ang_w2, aw2t, 128, blk-512, tsh);
    else if (blk < 2112) do_transpose(angproj_w, apjt, 3072, blk-576, tsh);
    else                 do_transpose(posproj_w, ppjt, 512, blk-2112, tsh);
    return;
  }
  blk -= NB_TR;
  if (blk < NB_PREP){
    int r = blk*256 + tid;
    int b = r / (SEQL*6);
    int rr = r - b*(SEQL*6);
    int l = rr / 6, j = rr - l*6;
    int bl = b*SEQL + l;
    int am = (j<3) ? angm[bl*3+j] : bondm[bl*3+(j-3)];
    int l2 = rr & (SEQL-1);            // tile(.,(1,6,1)) quirk
    int bl2 = b*SEQL + l2;
    int a2 = aa[bl2];
    int tm = mask_angle[bl2] && (a2!=0) && (a2!=2);
    amask8[r] = (unsigned char)(am != 0);
    teidx[r] = (tm && am) ? bl : T0ROW;
    return;
  }
  blk -= NB_PREP;
  {
    // dist: one wave per row
    int gw = blk*4 + (tid >> 6);
    int lane = tid & 63;
    float4 c = pk[gw];
    float out = 0.f;
    if (c.w >= 0.f){
      int rowbase = (gw >> 11) << 11;
      float s = 0.f, cnt = 0.f;
      for (int j = lane; j < SEQL; j += 64){
        float4 q = pk[rowbase + j];
        if (q.w == c.w){
          float dx = c.x-q.x, dy = c.y-q.y, dz = c.z-q.z;
          float sq = dx*dx+dy*dy+dz*dz;
          s += (sq>0.f) ? sqrtf(sq) : 0.f;
          cnt += 1.f;
        }
      }
      #pragma unroll
      for (int off=32; off>0; off>>=1){
        s   += __shfl_down(s, off);
        cnt += __shfl_down(cnt, off);
      }
      out = s / fmaxf(cnt, 1.f);
    }
    if (lane==0) dist[gw] = out;
  }
}

// ============== bf16 MFMA GEMM body: 128x64 tile, 512 thr (8 waves 4x2) =====
// BK=32, 16x16x32 MFMA, global_load_lds(16B), chunk-XOR swizzle (0-conflict).
// Epilogue: per-wave LDS transpose (16x36 f32, 2-way banks = free) ->
// lane owns (row, 8 cols) -> 16B vector stores/gathers.
// EPI: 0 gelu(v+bias)->bf16 | 1 v+bias->bf16 | 2 assemble->bf16
//      3 final(v+bias,cls/eos/pad)->fp32
struct EpiArgs {
  const float* bias;
  const bf16*  E;
  const int*   teidx;
  const unsigned char* amask;
  const float* unk;
  const int*   aa;
  const int*   pad;
  const float* cls;
  const float* eos;
  float*       outF;
  bf16*        outB;
  int          ldc;
};

template<int EPI>
__device__ __forceinline__ void gemm_body(const bf16* __restrict__ A, const bf16* __restrict__ Bt,
                                          int K, int bm, int bn, const EpiArgs& ea, char* smem){
  char* Al = smem;             // 128x32 bf16 = 8192 B
  char* Bl = smem + 8192;      // 64x32 bf16  = 4096 B
  const int tid = threadIdx.x;
  const int w = tid >> 6, lane = tid & 63;

  const int r = w*16 + (lane>>2);
  const int ch = lane & 3;
  const int cg = ch ^ ((r>>1)&3);
  const char* gA = (const char*)(A + (size_t)(bm+r)*K + cg*8);
  const bool doB = (w < 4);
  const char* gB = (const char*)(Bt + (size_t)(bn+r)*K + cg*8);
  char* lA = Al + w*1024;
  char* lB = Bl + w*1024;

  const int wm = (w>>1)*32, wn = (w&1)*32;
  const int lm = lane & 15, kq = lane >> 4;
  const int sw = kq ^ ((lm>>1)&3);

  f32x4 acc[2][2];
  #pragma unroll
  for (int i=0;i<2;i++)
    #pragma unroll
    for (int j=0;j<2;j++) acc[i][j] = (f32x4){0.f,0.f,0.f,0.f};

  for (int k0 = 0; k0 < K; k0 += 32){
    gload16(gA + (size_t)k0*2, lA);
    if (doB) gload16(gB + (size_t)k0*2, lB);
    __syncthreads();
    short8 af[2], bfr[2];
    #pragma unroll
    for (int t=0;t<2;t++) af[t]  = *(const short8*)(Al + (wm+t*16+lm)*64 + sw*16);
    #pragma unroll
    for (int t=0;t<2;t++) bfr[t] = *(const short8*)(Bl + (wn+t*16+lm)*64 + sw*16);
    #pragma unroll
    for (int mt=0;mt<2;mt++)
      #pragma unroll
      for (int nt=0;nt<2;nt++)
        acc[mt][nt] = __builtin_amdgcn_mfma_f32_16x16x32_bf16(af[mt], bfr[nt], acc[mt][nt], 0, 0, 0);
    __syncthreads();
  }

  // ---- per-wave LDS-transpose epilogue (regions disjoint; wave-sync only) --
  float* eps = (float*)smem + w*576;     // 16 rows x 36 f32
  const int erow = lane >> 2;
  const int ecg  = (lane & 3) * 8;
  #pragma unroll
  for (int mt=0; mt<2; mt++){
    #pragma unroll
    for (int nt=0; nt<2; nt++)
      #pragma unroll
      for (int rr=0; rr<4; rr++)
        eps[(kq*4+rr)*36 + nt*16 + lm] = acc[mt][nt][rr];
    __asm__ volatile("s_waitcnt lgkmcnt(0)" ::: "memory");
    float4 t0 = *(float4*)(eps + erow*36 + ecg);
    float4 t1 = *(float4*)(eps + erow*36 + ecg + 4);
    float v[8] = {t0.x,t0.y,t0.z,t0.w,t1.x,t1.y,t1.z,t1.w};
    __asm__ volatile("s_waitcnt lgkmcnt(0)" ::: "memory");
    int row = bm + wm + mt*16 + erow;
    int col = bn + wn + ecg;

    if (EPI==0 || EPI==1){
      float4 b0 = *(const float4*)(ea.bias+col), b1 = *(const float4*)(ea.bias+col+4);
      float bb[8] = {b0.x,b0.y,b0.z,b0.w,b1.x,b1.y,b1.z,b1.w};
      #pragma unroll
      for (int i=0;i<8;i++){
        v[i] += bb[i];
        if (EPI==0) v[i] = gelu_f(v[i]);
      }
      uint4 st;
      st.x = packbf2(v[0],v[1]); st.y = packbf2(v[2],v[3]);
      st.z = packbf2(v[4],v[5]); st.w = packbf2(v[6],v[7]);
      *(uint4*)(ea.outB + (size_t)row*ea.ldc + col) = st;
    } else if (EPI==2){
      if (!ea.amask[row]){
        float4 u0 = *(const float4*)(ea.unk+col), u1 = *(const float4*)(ea.unk+col+4);
        v[0]=u0.x;v[1]=u0.y;v[2]=u0.z;v[3]=u0.w;v[4]=u1.x;v[5]=u1.y;v[6]=u1.z;v[7]=u1.w;
      }
      uint4 evv = *(const uint4*)(ea.E + (size_t)ea.teidx[row]*DDIM + col);
      v[0]+=bflo(evv.x); v[1]+=bfhi(evv.x); v[2]+=bflo(evv.y); v[3]+=bfhi(evv.y);
      v[4]+=bflo(evv.z); v[5]+=bfhi(evv.z); v[6]+=bflo(evv.w); v[7]+=bfhi(evv.w);
      uint4 st;
      st.x = packbf2(v[0],v[1]); st.y = packbf2(v[2],v[3]);
      st.z = packbf2(v[4],v[5]); st.w = packbf2(v[6],v[7]);
      *(uint4*)(ea.outB + (size_t)row*ea.ldc + col) = st;
    } else {
      float4 b0 = *(const float4*)(ea.bias+col), b1 = *(const float4*)(ea.bias+col+4);
      v[0]+=b0.x; v[1]+=b0.y; v[2]+=b0.z; v[3]+=b0.w;
      v[4]+=b1.x; v[5]+=b1.y; v[6]+=b1.z; v[7]+=b1.w;
      int a = ea.aa[row];
      if (a==0){
        float4 c0 = *(const float4*)(ea.cls+col), c1 = *(const float4*)(ea.cls+col+4);
        v[0]=c0.x;v[1]=c0.y;v[2]=c0.z;v[3]=c0.w;v[4]=c1.x;v[5]=c1.y;v[6]=c1.z;v[7]=c1.w;
      } else if (a==2){
        float4 c0 = *(const float4*)(ea.eos+col), c1 = *(const float4*)(ea.eos+col+4);
        v[0]=c0.x;v[1]=c0.y;v[2]=c0.z;v[3]=c0.w;v[4]=c1.x;v[5]=c1.y;v[6]=c1.z;v[7]=c1.w;
      }
      if (ea.pad[row]){
        #pragma unroll
        for (int i=0;i<8;i++) v[i]=0.f;
      }
      *(float4*)(ea.outF + (size_t)row*ea.ldc + col)     = make_float4(v[0],v[1],v[2],v[3]);
      *(float4*)(ea.outF + (size_t)row*ea.ldc + col + 4) = make_float4(v[4],v[5],v[6],v[7]);
    }
  }
}

// ---- standalone 128x64 GEMM (TE MLP): grid = (M/128)*8 ----
template<int EPI>
__launch_bounds__(512, 8)
__global__ void gemm64_kernel(const bf16* __restrict__ A, const bf16* __restrict__ Bt,
                              int K, EpiArgs ea){
  __shared__ __align__(16) char smem[18432];
  int id = blockIdx.x;
  int m = id >> 3, n = id & 7;
  gemm_body<EPI>(A, Bt, K, m*128, n*64, ea, smem);
}

// ---- assemble GEMM (3072 blocks, XCD-banded) + posfeat (1024 blocks) ----
__launch_bounds__(512, 8)
__global__ void asm_posfeat_kernel(const bf16* __restrict__ Hang, const bf16* __restrict__ aw2t,
                                   EpiArgs ea,
                                   const float* __restrict__ dist, const int* __restrict__ aa,
                                   const int* __restrict__ mask_angle, const float* __restrict__ pw1,
                                   const float* __restrict__ pw2, const float* __restrict__ unkpos,
                                   const bf16* __restrict__ E, bf16* __restrict__ PF){
  __shared__ __align__(16) char smem[18432];
  int id = blockIdx.x;
  if (id < 3072){
    int c = id & 7, q = id >> 3;
    int n = q & 7, mh = q >> 3;
    int m = mh*8 + c;                   // 8 n-blocks of band m share id%8 -> same XCD
    gemm_body<2>(Hang, aw2t, AHID, m*128, n*64, ea, smem);
    return;
  }
  int gidx = (id-3072)*512 + threadIdx.x;
  int row = gidx >> 6;
  int db = (gidx & 63) * 8;
  int a = aa[row];
  bool ce = (a==0) || (a==2);
  float g = ce ? 0.f : gelu_f(dist[row]*pw1[0]);
  bool tm = mask_angle[row] && !ce;
  uint4 ev = *(const uint4*)(E + (size_t)(tm ? row : T0ROW)*DDIM + db);
  float te[8] = {bflo(ev.x),bfhi(ev.x),bflo(ev.y),bfhi(ev.y),bflo(ev.z),bfhi(ev.z),bflo(ev.w),bfhi(ev.w)};
  float bsv[8];
  if (ce){
    float4 u0 = *(const float4*)(unkpos+db), u1 = *(const float4*)(unkpos+db+4);
    bsv[0]=u0.x;bsv[1]=u0.y;bsv[2]=u0.z;bsv[3]=u0.w;bsv[4]=u1.x;bsv[5]=u1.y;bsv[6]=u1.z;bsv[7]=u1.w;
  } else {
    float4 w0 = *(const float4*)(pw2+db), w1 = *(const float4*)(pw2+db+4);
    bsv[0]=g*w0.x;bsv[1]=g*w0.y;bsv[2]=g*w0.z;bsv[3]=g*w0.w;bsv[4]=g*w1.x;bsv[5]=g*w1.y;bsv[6]=g*w1.z;bsv[7]=g*w1.w;
  }
  uint4 st;
  st.x = packbf2(bsv[0]+te[0], bsv[1]+te[1]);
  st.y = packbf2(bsv[2]+te[2], bsv[3]+te[3]);
  st.z = packbf2(bsv[4]+te[4], bsv[5]+te[5]);
  st.w = packbf2(bsv[6]+te[6], bsv[7]+te[7]);
  *(uint4*)(PF + (size_t)row*DDIM + db) = st;
}

// ---- merged projections: angproj (512 blocks) + posproj (512 blocks) ----
__launch_bounds__(512, 8)
__global__ void proj_kernel(const bf16* __restrict__ AF, const bf16* __restrict__ apjt, EpiArgs eaA,
                            const bf16* __restrict__ PF, const bf16* __restrict__ ppjt, EpiArgs eaP){
  __shared__ __align__(16) char smem[18432];
  int id = blockIdx.x;
  bool po = (id >= 512);
  int id2 = po ? id-512 : id;
  int c = id2 & 7, q = id2 >> 3;
  int n = q & 7, mh = q >> 3;
  int m = mh*8 + c;
  if (!po) gemm_body<3>(AF, apjt, 6*DDIM, m*128, n*64, eaA, smem);
  else     gemm_body<3>(PF, ppjt, DDIM,  m*128, n*64, eaP, smem);
}

extern "C" void kernel_launch(void* const* d_in, const int* in_sizes, int n_in,
                              void* d_out, int out_size, void* d_ws, size_t ws_size,
                              hipStream_t stream){
  const float* pos        = (const float*)d_in[0];
  const float* angle      = (const float*)d_in[1];
  const int*   padm       = (const int*)d_in[2];
  const int*   mask_angle = (const int*)d_in[5];
  const int*   angle_mask = (const int*)d_in[6];
  const int*   bond_mask  = (const int*)d_in[7];
  const float* time_pos   = (const float*)d_in[8];
  const int*   aa         = (const int*)d_in[10];
  const float* ang_w1     = (const float*)d_in[11];
  const float* ang_w2     = (const float*)d_in[12];
  const float* pos_w1     = (const float*)d_in[13];
  const float* pos_w2     = (const float*)d_in[14];
  const float* te_w1      = (const float*)d_in[15];
  const float* te_b1      = (const float*)d_in[16];
  const float* te_w2      = (const float*)d_in[17];
  const float* te_b2      = (const float*)d_in[18];
  const float* angproj_w  = (const float*)d_in[19];
  const float* angproj_b  = (const float*)d_in[20];
  const float* posproj_w  = (const float*)d_in[21];
  const float* posproj_b  = (const float*)d_in[22];
  const float* cls_w      = (const float*)d_in[23];
  const float* eos_w      = (const float*)d_in[24];
  const float* unkang     = (const float*)d_in[25];
  const float* unkpos     = (const float*)d_in[26];

  char* ws = (char*)d_ws;
  size_t off = 0;
  auto alloc = [&](size_t bytes)->char*{
    char* p = ws + off;
    off += (bytes + 255) & ~(size_t)255;
    return p;
  };
  float* dist   = (float*)alloc((size_t)NROWS*4);
  float4* pk    = (float4*)alloc((size_t)NROWS*16);
  unsigned char* amask8 = (unsigned char*)alloc(NANG);
  int*   teidx  = (int*)  alloc((size_t)NANG*4);
  bf16*  e      = (bf16*) alloc((size_t)MTE*DDIM*2);
  bf16*  H1     = (bf16*) alloc((size_t)MTE*DDIM*2);
  bf16*  E      = (bf16*) alloc((size_t)MTE*DDIM*2);
  bf16*  Hang   = (bf16*) alloc((size_t)NANG*AHID*2);
  bf16*  AF     = (bf16*) alloc((size_t)NANG*DDIM*2);
  bf16*  PF     = (bf16*) alloc((size_t)NROWS*DDIM*2);
  bf16*  tw1t   = (bf16*) alloc((size_t)DDIM*DDIM*2);
  bf16*  tw2t   = (bf16*) alloc((size_t)DDIM*DDIM*2);
  bf16*  aw2t   = (bf16*) alloc((size_t)DDIM*AHID*2);
  bf16*  apjt   = (bf16*) alloc((size_t)DDIM*6*DDIM*2);
  bf16*  ppjt   = (bf16*) alloc((size_t)DDIM*DDIM*2);

  float* out = (float*)d_out;
  dim3 b256(256), b512(512);

  // 1. scan + pk pack (1 block)
  scan_pack_kernel<<<dim3(1), b256, 0, stream>>>(aa, pos, pk);

  // 2. prologue: anghid + sinemb + transposes + prep + dist
  prologue_kernel<<<dim3(NB_TOTAL), b256, 0, stream>>>(
      angle, angle_mask, bond_mask, mask_angle, aa, ang_w1, time_pos,
      te_w1, te_w2, ang_w2, angproj_w, posproj_w, pk,
      Hang, e, tw1t, tw2t, aw2t, apjt, ppjt, amask8, teidx, dist);

  // 3. time-embedding MLP (8320 rows incl. t0)
  EpiArgs ea{};
  ea.bias = te_b1; ea.outB = H1; ea.ldc = DDIM;
  gemm64_kernel<0><<<dim3((MTE/128)*8), b512, 0, stream>>>(e, tw1t, DDIM, ea);
  ea.bias = te_b2; ea.outB = E;
  gemm64_kernel<1><<<dim3((MTE/128)*8), b512, 0, stream>>>(H1, tw2t, DDIM, ea);

  // 4. assemble GEMM -> AF bf16 [49152,512]  +  posfeat -> PF
  EpiArgs ea2{};
  ea2.E = E; ea2.teidx = teidx; ea2.amask = amask8; ea2.unk = unkang;
  ea2.outB = AF; ea2.ldc = DDIM;
  asm_posfeat_kernel<<<dim3(3072+1024), b512, 0, stream>>>(
      Hang, aw2t, ea2, dist, aa, mask_angle, pos_w1, pos_w2, unkpos, E, PF);

  // 5. merged projections -> out (angproj cols 0..511, posproj cols 512..1023)
  EpiArgs ea3{};
  ea3.bias = angproj_b; ea3.aa = aa; ea3.pad = padm; ea3.cls = cls_w; ea3.eos = eos_w;
  ea3.outF = out; ea3.ldc = 1024;
  EpiArgs ea4{};
  ea4.bias = posproj_b; ea4.aa = aa; ea4.pad = padm; ea4.cls = cls_w + DDIM; ea4.eos = eos_w + DDIM;
  ea4.outF = out + DDIM; ea4.ldc = 1024;
  proj_kernel<<<dim3(1024), b512, 0, stream>>>(AF, apjt, ea3, PF, ppjt, ea4);
}